// Round 3
// baseline (81.398 us; speedup 1.0000x reference)
//
#include <hip/hip_runtime.h>
#include <hip/hip_bf16.h>
#include <math.h>

// Problem constants
#define BS_    512
#define NA_    10
#define NE_    11
#define NAL_   9
#define H_     64
#define HEADS_ 4
#define EDIM_  8
#define ADIM_  8
#define OWN_   14
#define HYP_   64
#define NTOT_  (BS_*NA_)   // 5120

// ws float offsets (folded weights)
#define WBIG_OFF 0         // [1040][64]: rows 0..511 W2e'', 512..1023 W2a'', 1024..1031 b2e', 1032..1039 b2a'
#define WCT2_OFF 66560     // [64][64]  WCT2[k][h'] (transposed WcT)
#define WB_OFF   70656     // [64]
#define BB_OFF   70720     // [64]
#define CC_OFF   70784     // [1]
#define FC1T_OFF 70848     // [14][64]  fc1_own_w transposed
#define WGRU_OFF 71744     // [64][64][6] {ih_r,hh_r,ih_z,hh_z,ih_n,hh_n} per (j,k)
#define WS_FLOATS 96320

__global__ __launch_bounds__(256) void prep_kernel(
    const float* __restrict__ fc1_own_w,
    const float* __restrict__ he_w2, const float* __restrict__ he_b2,
    const float* __restrict__ ha_w2, const float* __restrict__ ha_b2,
    const float* __restrict__ merge_in_w,
    const float* __restrict__ gru_w_ih, const float* __restrict__ gru_w_hh,
    const float* __restrict__ merge_out_w,
    float* __restrict__ ws)
{
    const int tid = blockIdx.x * blockDim.x + threadIdx.x;

    float wo0, wo1, wo2, wo3;
    {
        float e0 = expf(merge_out_w[0]), e1 = expf(merge_out_w[1]);
        float e2 = expf(merge_out_w[2]), e3 = expf(merge_out_w[3]);
        float inv = 1.0f / (e0 + e1 + e2 + e3);
        wo0 = e0*inv; wo1 = e1*inv; wo2 = e2*inv; wo3 = e3*inv;
    }

    if (tid < 66560) {
        const int idx = tid >> 6;   // 0..1039
        const int hp  = tid & 63;
        float e0 = expf(merge_in_w[0*64 + hp]), e1 = expf(merge_in_w[1*64 + hp]);
        float e2 = expf(merge_in_w[2*64 + hp]), e3 = expf(merge_in_w[3*64 + hp]);
        float inv = 1.0f / (e0 + e1 + e2 + e3);
        const float wi[4] = { e0*inv, e1*inv, e2*inv, e3*inv };
        float v = 0.f;
        if (idx < 512) {
            const int e = idx >> 6, k = idx & 63;
#pragma unroll
            for (int hd = 0; hd < 4; hd++)
                v += wi[hd] * he_w2[(e*256 + hd*64 + hp)*64 + k];
        } else if (idx < 1024) {
            const int e = (idx - 512) >> 6, k = idx & 63;
#pragma unroll
            for (int hd = 0; hd < 4; hd++)
                v += wi[hd] * ha_w2[(e*256 + hd*64 + hp)*64 + k];
        } else if (idx < 1032) {
            const int e = idx - 1024;
#pragma unroll
            for (int hd = 0; hd < 4; hd++)
                v += wi[hd] * he_b2[e*256 + hd*64 + hp];
        } else {
            const int e = idx - 1032;
#pragma unroll
            for (int hd = 0; hd < 4; hd++)
                v += wi[hd] * ha_b2[e*256 + hd*64 + hp];
        }
        ws[WBIG_OFF + tid] = v;
    } else if (tid < 70656) {
        // WCT2[k][h'] = sum_hd wo_hd * he_w2[(2048 + hd*64 + h')*64 + k]
        const int t = tid - 66560;
        const int k = t >> 6, hp = t & 63;
        float v = wo0 * he_w2[(2048 + 0*64 + hp)*64 + k]
                + wo1 * he_w2[(2048 + 1*64 + hp)*64 + k]
                + wo2 * he_w2[(2048 + 2*64 + hp)*64 + k]
                + wo3 * he_w2[(2048 + 3*64 + hp)*64 + k];
        ws[WCT2_OFF + t] = v;
    } else if (tid < 70720) {
        const int k = tid - 70656;
        float v = wo0*he_w2[(2304+0)*64 + k] + wo1*he_w2[(2304+1)*64 + k]
                + wo2*he_w2[(2304+2)*64 + k] + wo3*he_w2[(2304+3)*64 + k];
        ws[WB_OFF + k] = v;
    } else if (tid < 70784) {
        const int hp = tid - 70720;
        float v = wo0*he_b2[2048 + 0*64 + hp] + wo1*he_b2[2048 + 1*64 + hp]
                + wo2*he_b2[2048 + 2*64 + hp] + wo3*he_b2[2048 + 3*64 + hp];
        ws[BB_OFF + hp] = v;
    } else if (tid == 70784) {
        ws[CC_OFF] = wo0*he_b2[2304] + wo1*he_b2[2305] + wo2*he_b2[2306] + wo3*he_b2[2307];
    } else if (tid < 70848) {
        // pad
    } else if (tid < 71744) {
        const int t = tid - 70848; const int j = t >> 6, hp = t & 63;
        ws[FC1T_OFF + t] = fc1_own_w[hp*OWN_ + j];
    } else if (tid < 96320) {
        // WGRU[j][k][6] = {ih_r, hh_r, ih_z, hh_z, ih_n, hh_n} at (j,k)
        const int t = tid - 71744;       // 0..24575
        const int j = t / 384;
        const int r = t - j*384;
        const int k = r / 6;
        const int c = r - k*6;
        const int g = c >> 1;
        const float* src = (c & 1) ? gru_w_hh : gru_w_ih;
        ws[WGRU_OFF + t] = src[(g*64 + k)*64 + j];
    }
}

__device__ __forceinline__ float wave_red(float v) {
#pragma unroll
    for (int off = 32; off; off >>= 1) v += __shfl_xor(v, off);
    return v;
}

__global__ __launch_bounds__(256) void main_kernel(
    const float* __restrict__ own_feats,
    const float* __restrict__ enemy_feats,
    const float* __restrict__ ally_feats,
    const float* __restrict__ hidden_state,
    const int*   __restrict__ agent_idx,
    const int*   __restrict__ last_act,
    const float* __restrict__ fc1_own_b,
    const float* __restrict__ agent_emb,
    const float* __restrict__ action_emb,
    const float* __restrict__ he_w1,
    const float* __restrict__ he_b1,
    const float* __restrict__ ha_w1,
    const float* __restrict__ ha_b1,
    const float* __restrict__ fc2_w,
    const float* __restrict__ fc2_b,
    const float* __restrict__ gru_b_ih,
    const float* __restrict__ gru_b_hh,
    const float* __restrict__ ws,
    float* __restrict__ out)
{
    const int tid  = threadIdx.x;
    const int w    = tid >> 6;        // wave id 0..3 == agent slot
    const int lane = tid & 63;
    const int n    = blockIdx.x * 4 + w;

    __shared__ float a_lds[4][1040];
    __shared__ float pemb[4][4][64];
    __shared__ float xh_lds[4][64][2];   // [agent][j][{x,h}]
    __shared__ float hh_lds[4][64];

    // ================= Phase 1: per-agent activations (wave = agent) ========
    float h_e[NE_];
    float embo, hin_reg;
    {
        const float4 w1a  = *(const float4*)(he_w1 + lane*8);
        const float4 w1b  = *(const float4*)(he_w1 + lane*8 + 4);
        const float  hb1  = he_b1[lane];

        float ps[8] = {0,0,0,0,0,0,0,0};
#pragma unroll
        for (int ei = 0; ei < NE_; ei++) {
            const float* ef = enemy_feats + (size_t)(n*NE_ + ei)*EDIM_;
            const float4 e0 = *(const float4*)ef;
            const float4 e1 = *(const float4*)(ef + 4);
            float h = hb1;
            h = fmaf(e0.x, w1a.x, h); h = fmaf(e0.y, w1a.y, h);
            h = fmaf(e0.z, w1a.z, h); h = fmaf(e0.w, w1a.w, h);
            h = fmaf(e1.x, w1b.x, h); h = fmaf(e1.y, w1b.y, h);
            h = fmaf(e1.z, w1b.z, h); h = fmaf(e1.w, w1b.w, h);
            h = fmaxf(h, 0.f);
            h_e[ei] = h;
            ps[0] = fmaf(e0.x, h, ps[0]); ps[1] = fmaf(e0.y, h, ps[1]);
            ps[2] = fmaf(e0.z, h, ps[2]); ps[3] = fmaf(e0.w, h, ps[3]);
            ps[4] = fmaf(e1.x, h, ps[4]); ps[5] = fmaf(e1.y, h, ps[5]);
            ps[6] = fmaf(e1.z, h, ps[6]); ps[7] = fmaf(e1.w, h, ps[7]);
        }
#pragma unroll
        for (int e = 0; e < 8; e++) a_lds[w][e*64 + lane] = ps[e];

        const float4 wa1a = *(const float4*)(ha_w1 + lane*8);
        const float4 wa1b = *(const float4*)(ha_w1 + lane*8 + 4);
        const float  hba1 = ha_b1[lane];
        float pa[8] = {0,0,0,0,0,0,0,0};
#pragma unroll
        for (int ai = 0; ai < NAL_; ai++) {
            const float* af = ally_feats + (size_t)(n*NAL_ + ai)*ADIM_;
            const float4 a0 = *(const float4*)af;
            const float4 a1 = *(const float4*)(af + 4);
            float h = hba1;
            h = fmaf(a0.x, wa1a.x, h); h = fmaf(a0.y, wa1a.y, h);
            h = fmaf(a0.z, wa1a.z, h); h = fmaf(a0.w, wa1a.w, h);
            h = fmaf(a1.x, wa1b.x, h); h = fmaf(a1.y, wa1b.y, h);
            h = fmaf(a1.z, wa1b.z, h); h = fmaf(a1.w, wa1b.w, h);
            h = fmaxf(h, 0.f);
            pa[0] = fmaf(a0.x, h, pa[0]); pa[1] = fmaf(a0.y, h, pa[1]);
            pa[2] = fmaf(a0.z, h, pa[2]); pa[3] = fmaf(a0.w, h, pa[3]);
            pa[4] = fmaf(a1.x, h, pa[4]); pa[5] = fmaf(a1.y, h, pa[5]);
            pa[6] = fmaf(a1.z, h, pa[6]); pa[7] = fmaf(a1.w, h, pa[7]);
        }
#pragma unroll
        for (int e = 0; e < 8; e++) a_lds[w][512 + e*64 + lane] = pa[e];

        if (lane < 8) {
            float s = 0.f;
            for (int ei = 0; ei < NE_; ei++) s += enemy_feats[(size_t)(n*NE_ + ei)*EDIM_ + lane];
            a_lds[w][1024 + lane] = s;
        } else if (lane < 16) {
            const int p = lane - 8;
            float s = 0.f;
            for (int ai = 0; ai < NAL_; ai++) s += ally_feats[(size_t)(n*NAL_ + ai)*ADIM_ + p];
            a_lds[w][1032 + p] = s;
        }

        float e = fc1_own_b[lane];
        const float* ow = own_feats + (size_t)n*OWN_;
#pragma unroll
        for (int j = 0; j < OWN_; j++) e = fmaf(ow[j], ws[FC1T_OFF + j*64 + lane], e);
        e += agent_emb[agent_idx[n]*64 + lane];
        e += action_emb[last_act[n]*64 + lane];
        embo = e;

        hin_reg = hidden_state[(size_t)n*64 + lane];
        xh_lds[w][lane][1] = hin_reg;
    }
    __syncthreads();

    // ================= Phase 2: folded dot, K-split, SW-prefetched ==========
    {
        float acc[4];
#pragma unroll
        for (int nn = 0; nn < 4; nn++) acc[nn] = (nn == w) ? embo : 0.f;

        const int r0 = w * 260;
        const float* pw = ws + WBIG_OFF + r0*64 + lane;
        float c0 = pw[0], c1 = pw[64], c2 = pw[128], c3 = pw[192];
        pw += 256;
        for (int it = 0; it < 65; ++it) {
            // prefetch next 4 rows (last iter over-reads into WCT2 region: safe, unused)
            const float n0 = pw[0], n1 = pw[64], n2 = pw[128], n3 = pw[192];
            pw += 256;
            const int idx = r0 + it*4;
#pragma unroll
            for (int nn = 0; nn < 4; nn++) {
                const float4 aa = *(const float4*)&a_lds[nn][idx];
                float a = acc[nn];
                a = fmaf(aa.x, c0, a);
                a = fmaf(aa.y, c1, a);
                a = fmaf(aa.z, c2, a);
                a = fmaf(aa.w, c3, a);
                acc[nn] = a;
            }
            c0 = n0; c1 = n1; c2 = n2; c3 = n3;
        }
#pragma unroll
        for (int nn = 0; nn < 4; nn++) pemb[w][nn][lane] = acc[nn];
    }
    __syncthreads();

    // ================= Finalize emb + GRU + epilogue: all wave-private ======
    {
        const float emb = pemb[0][w][lane] + pemb[1][w][lane]
                        + pemb[2][w][lane] + pemb[3][w][lane];
        xh_lds[w][lane][0] = fmaxf(emb, 0.f);
    }
    // same-wave LDS RAW: lgkmcnt handled by compiler, no barrier needed

    float hh;
    {
        float gr = gru_b_ih[lane], gz = gru_b_ih[64 + lane], gn = gru_b_ih[128 + lane];
        float hr = gru_b_hh[lane], hz = gru_b_hh[64 + lane], hn = gru_b_hh[128 + lane];
        const float* wg = ws + WGRU_OFF + lane*6;
#pragma unroll 4
        for (int j = 0; j < 64; ++j) {
            const float2 xh = *(const float2*)&xh_lds[w][j][0];
            const float2 p0 = *(const float2*)(wg + 0);
            const float2 p1 = *(const float2*)(wg + 2);
            const float2 p2 = *(const float2*)(wg + 4);
            wg += 384;
            gr = fmaf(xh.x, p0.x, gr); hr = fmaf(xh.y, p0.y, hr);
            gz = fmaf(xh.x, p1.x, gz); hz = fmaf(xh.y, p1.y, hz);
            gn = fmaf(xh.x, p2.x, gn); hn = fmaf(xh.y, p2.y, hn);
        }
        const float r = 1.f / (1.f + expf(-(gr + hr)));
        const float z = 1.f / (1.f + expf(-(gz + hz)));
        const float t = tanhf(gn + r * hn);
        hh = (1.f - z) * t + z * hin_reg;
        hh_lds[w][lane] = hh;
    }

    {
        float* o = out + (size_t)n*17;

        // q_normal: 6 outputs
#pragma unroll
        for (int l = 0; l < 6; l++) {
            const float p = wave_red(hh * fc2_w[l*64 + lane]);
            if (lane == 0) o[l] = p + fc2_b[l];
        }

        // vv = Wc.hh + wb  (transposed WCT2[k][h'], float4)
        float vv = ws[WB_OFF + lane];
        const float* wct = ws + WCT2_OFF + lane*64;
#pragma unroll
        for (int j4 = 0; j4 < 64; j4 += 4) {
            const float4 hh4 = *(const float4*)&hh_lds[w][j4];
            const float4 wv  = *(const float4*)(wct + j4);
            vv = fmaf(hh4.x, wv.x, vv);
            vv = fmaf(hh4.y, wv.y, vv);
            vv = fmaf(hh4.z, wv.z, vv);
            vv = fmaf(hh4.w, wv.w, vv);
        }

        // sn = hh.bb + cc
        const float sn = wave_red(hh * ws[BB_OFF + lane]) + ws[CC_OFF];

        // q_attack
#pragma unroll
        for (int ei = 0; ei < NE_; ei++) {
            const float q = wave_red(vv * h_e[ei]);
            if (lane == 0) o[6 + ei] = q + sn;
        }
    }
}

extern "C" void kernel_launch(void* const* d_in, const int* in_sizes, int n_in,
                              void* d_out, int out_size, void* d_ws, size_t ws_size,
                              hipStream_t stream)
{
    const float* own_feats   = (const float*)d_in[0];
    const float* enemy_feats = (const float*)d_in[1];
    const float* ally_feats  = (const float*)d_in[2];
    const float* hidden      = (const float*)d_in[3];
    const int*   agent_idx   = (const int*)d_in[4];
    const int*   last_act    = (const int*)d_in[5];
    const float* fc1_own_w   = (const float*)d_in[6];
    const float* fc1_own_b   = (const float*)d_in[7];
    const float* agent_emb   = (const float*)d_in[8];
    const float* action_emb  = (const float*)d_in[9];
    const float* he_w1       = (const float*)d_in[10];
    const float* he_b1       = (const float*)d_in[11];
    const float* he_w2       = (const float*)d_in[12];
    const float* he_b2       = (const float*)d_in[13];
    const float* ha_w1       = (const float*)d_in[14];
    const float* ha_b1       = (const float*)d_in[15];
    const float* ha_w2       = (const float*)d_in[16];
    const float* ha_b2       = (const float*)d_in[17];
    const float* merge_in_w  = (const float*)d_in[18];
    const float* gru_w_ih    = (const float*)d_in[19];
    const float* gru_w_hh    = (const float*)d_in[20];
    const float* gru_b_ih    = (const float*)d_in[21];
    const float* gru_b_hh    = (const float*)d_in[22];
    const float* fc2_w       = (const float*)d_in[23];
    const float* fc2_b       = (const float*)d_in[24];
    const float* merge_out_w = (const float*)d_in[25];
    float* out = (float*)d_out;
    float* ws  = (float*)d_ws;

    hipLaunchKernelGGL(prep_kernel, dim3(377), dim3(256), 0, stream,
                       fc1_own_w, he_w2, he_b2, ha_w2, ha_b2, merge_in_w,
                       gru_w_ih, gru_w_hh, merge_out_w, ws);
    hipLaunchKernelGGL(main_kernel, dim3(NTOT_/4), dim3(256), 0, stream,
                       own_feats, enemy_feats, ally_feats, hidden, agent_idx, last_act,
                       fc1_own_b, agent_emb, action_emb, he_w1, he_b1, ha_w1, ha_b1,
                       fc2_w, fc2_b, gru_b_ih, gru_b_hh, ws, out);
}

// Round 4
// 67.090 us; speedup vs baseline: 1.2133x; 1.2133x over previous
//
#include <hip/hip_runtime.h>
#include <hip/hip_bf16.h>
#include <math.h>

// Problem constants
#define BS_    512
#define NA_    10
#define NE_    11
#define NAL_   9
#define H_     64
#define HEADS_ 4
#define EDIM_  8
#define ADIM_  8
#define OWN_   14
#define HYP_   64
#define NTOT_  (BS_*NA_)   // 5120

// ws float offsets (folded weights)
#define WBIG_OFF 0         // [1040][64]
#define WCT2_OFF 66560     // [64][64]  WCT2[k][h']
#define WB_OFF   70656     // [64]
#define BB_OFF   70720     // [64]
#define CC_OFF   70784     // [1]
#define FC1T_OFF 70848     // [14][64]
#define IHT_OFF  71744     // [64][192]
#define HHT_OFF  84032     // [64][192]
#define WS_FLOATS 96320

__global__ __launch_bounds__(256) void prep_kernel(
    const float* __restrict__ fc1_own_w,
    const float* __restrict__ he_w2, const float* __restrict__ he_b2,
    const float* __restrict__ ha_w2, const float* __restrict__ ha_b2,
    const float* __restrict__ merge_in_w,
    const float* __restrict__ gru_w_ih, const float* __restrict__ gru_w_hh,
    const float* __restrict__ merge_out_w,
    float* __restrict__ ws)
{
    const int tid = blockIdx.x * blockDim.x + threadIdx.x;

    float wo0, wo1, wo2, wo3;
    {
        float e0 = expf(merge_out_w[0]), e1 = expf(merge_out_w[1]);
        float e2 = expf(merge_out_w[2]), e3 = expf(merge_out_w[3]);
        float inv = 1.0f / (e0 + e1 + e2 + e3);
        wo0 = e0*inv; wo1 = e1*inv; wo2 = e2*inv; wo3 = e3*inv;
    }

    if (tid < 66560) {
        const int idx = tid >> 6;   // 0..1039
        const int hp  = tid & 63;
        float e0 = expf(merge_in_w[0*64 + hp]), e1 = expf(merge_in_w[1*64 + hp]);
        float e2 = expf(merge_in_w[2*64 + hp]), e3 = expf(merge_in_w[3*64 + hp]);
        float inv = 1.0f / (e0 + e1 + e2 + e3);
        const float wi[4] = { e0*inv, e1*inv, e2*inv, e3*inv };
        float v = 0.f;
        if (idx < 512) {
            const int e = idx >> 6, k = idx & 63;
#pragma unroll
            for (int hd = 0; hd < 4; hd++)
                v += wi[hd] * he_w2[(e*256 + hd*64 + hp)*64 + k];
        } else if (idx < 1024) {
            const int e = (idx - 512) >> 6, k = idx & 63;
#pragma unroll
            for (int hd = 0; hd < 4; hd++)
                v += wi[hd] * ha_w2[(e*256 + hd*64 + hp)*64 + k];
        } else if (idx < 1032) {
            const int e = idx - 1024;
#pragma unroll
            for (int hd = 0; hd < 4; hd++)
                v += wi[hd] * he_b2[e*256 + hd*64 + hp];
        } else {
            const int e = idx - 1032;
#pragma unroll
            for (int hd = 0; hd < 4; hd++)
                v += wi[hd] * ha_b2[e*256 + hd*64 + hp];
        }
        ws[WBIG_OFF + tid] = v;
    } else if (tid < 70656) {
        const int t = tid - 66560;
        const int k = t >> 6, hp = t & 63;
        float v = wo0 * he_w2[(2048 + 0*64 + hp)*64 + k]
                + wo1 * he_w2[(2048 + 1*64 + hp)*64 + k]
                + wo2 * he_w2[(2048 + 2*64 + hp)*64 + k]
                + wo3 * he_w2[(2048 + 3*64 + hp)*64 + k];
        ws[WCT2_OFF + t] = v;
    } else if (tid < 70720) {
        const int k = tid - 70656;
        float v = wo0*he_w2[(2304+0)*64 + k] + wo1*he_w2[(2304+1)*64 + k]
                + wo2*he_w2[(2304+2)*64 + k] + wo3*he_w2[(2304+3)*64 + k];
        ws[WB_OFF + k] = v;
    } else if (tid < 70784) {
        const int hp = tid - 70720;
        float v = wo0*he_b2[2048 + 0*64 + hp] + wo1*he_b2[2048 + 1*64 + hp]
                + wo2*he_b2[2048 + 2*64 + hp] + wo3*he_b2[2048 + 3*64 + hp];
        ws[BB_OFF + hp] = v;
    } else if (tid == 70784) {
        ws[CC_OFF] = wo0*he_b2[2304] + wo1*he_b2[2305] + wo2*he_b2[2306] + wo3*he_b2[2307];
    } else if (tid < 70848) {
        // pad
    } else if (tid < 71744) {
        const int t = tid - 70848; const int j = t >> 6, hp = t & 63;
        ws[FC1T_OFF + t] = fc1_own_w[hp*OWN_ + j];
    } else if (tid < 84032) {
        const int t = tid - 71744; const int j = t / 192, g = t % 192;
        ws[IHT_OFF + t] = gru_w_ih[g*64 + j];
    } else if (tid < 96320) {
        const int t = tid - 84032; const int j = t / 192, g = t % 192;
        ws[HHT_OFF + t] = gru_w_hh[g*64 + j];
    }
}

__device__ __forceinline__ float wave_red(float v) {
#pragma unroll
    for (int off = 32; off; off >>= 1) v += __shfl_xor(v, off);
    return v;
}

__global__ __launch_bounds__(256) void main_kernel(
    const float* __restrict__ own_feats,
    const float* __restrict__ enemy_feats,
    const float* __restrict__ ally_feats,
    const float* __restrict__ hidden_state,
    const int*   __restrict__ agent_idx,
    const int*   __restrict__ last_act,
    const float* __restrict__ fc1_own_b,
    const float* __restrict__ agent_emb,
    const float* __restrict__ action_emb,
    const float* __restrict__ he_w1,
    const float* __restrict__ he_b1,
    const float* __restrict__ ha_w1,
    const float* __restrict__ ha_b1,
    const float* __restrict__ fc2_w,
    const float* __restrict__ fc2_b,
    const float* __restrict__ gru_b_ih,
    const float* __restrict__ gru_b_hh,
    const float* __restrict__ ws,
    float* __restrict__ out)
{
    const int tid  = threadIdx.x;
    const int w    = tid >> 6;        // wave id 0..3 == agent slot
    const int lane = tid & 63;
    const int n    = blockIdx.x * 4 + w;

    __shared__ float a_lds[4][1040];
    __shared__ float pemb[4][4][64];
    __shared__ float x_lds[4][68];
    __shared__ float hin_lds[4][68];
    __shared__ float hh_lds[4][68];

    // ================= Phase 1: per-agent activations (wave = agent) ========
    float h_e[NE_];
    float embo;
    {
        const float4 w1a  = *(const float4*)(he_w1 + lane*8);
        const float4 w1b  = *(const float4*)(he_w1 + lane*8 + 4);
        const float  hb1  = he_b1[lane];

        float ps[8] = {0,0,0,0,0,0,0,0};
#pragma unroll
        for (int ei = 0; ei < NE_; ei++) {
            const float* ef = enemy_feats + (size_t)(n*NE_ + ei)*EDIM_;
            const float4 e0 = *(const float4*)ef;
            const float4 e1 = *(const float4*)(ef + 4);
            float h = hb1;
            h = fmaf(e0.x, w1a.x, h); h = fmaf(e0.y, w1a.y, h);
            h = fmaf(e0.z, w1a.z, h); h = fmaf(e0.w, w1a.w, h);
            h = fmaf(e1.x, w1b.x, h); h = fmaf(e1.y, w1b.y, h);
            h = fmaf(e1.z, w1b.z, h); h = fmaf(e1.w, w1b.w, h);
            h = fmaxf(h, 0.f);
            h_e[ei] = h;
            ps[0] = fmaf(e0.x, h, ps[0]); ps[1] = fmaf(e0.y, h, ps[1]);
            ps[2] = fmaf(e0.z, h, ps[2]); ps[3] = fmaf(e0.w, h, ps[3]);
            ps[4] = fmaf(e1.x, h, ps[4]); ps[5] = fmaf(e1.y, h, ps[5]);
            ps[6] = fmaf(e1.z, h, ps[6]); ps[7] = fmaf(e1.w, h, ps[7]);
        }
#pragma unroll
        for (int e = 0; e < 8; e++) a_lds[w][e*64 + lane] = ps[e];

        const float4 wa1a = *(const float4*)(ha_w1 + lane*8);
        const float4 wa1b = *(const float4*)(ha_w1 + lane*8 + 4);
        const float  hba1 = ha_b1[lane];
        float pa[8] = {0,0,0,0,0,0,0,0};
#pragma unroll
        for (int ai = 0; ai < NAL_; ai++) {
            const float* af = ally_feats + (size_t)(n*NAL_ + ai)*ADIM_;
            const float4 a0 = *(const float4*)af;
            const float4 a1 = *(const float4*)(af + 4);
            float h = hba1;
            h = fmaf(a0.x, wa1a.x, h); h = fmaf(a0.y, wa1a.y, h);
            h = fmaf(a0.z, wa1a.z, h); h = fmaf(a0.w, wa1a.w, h);
            h = fmaf(a1.x, wa1b.x, h); h = fmaf(a1.y, wa1b.y, h);
            h = fmaf(a1.z, wa1b.z, h); h = fmaf(a1.w, wa1b.w, h);
            h = fmaxf(h, 0.f);
            pa[0] = fmaf(a0.x, h, pa[0]); pa[1] = fmaf(a0.y, h, pa[1]);
            pa[2] = fmaf(a0.z, h, pa[2]); pa[3] = fmaf(a0.w, h, pa[3]);
            pa[4] = fmaf(a1.x, h, pa[4]); pa[5] = fmaf(a1.y, h, pa[5]);
            pa[6] = fmaf(a1.z, h, pa[6]); pa[7] = fmaf(a1.w, h, pa[7]);
        }
#pragma unroll
        for (int e = 0; e < 8; e++) a_lds[w][512 + e*64 + lane] = pa[e];

        if (lane < 8) {
            float s = 0.f;
            for (int ei = 0; ei < NE_; ei++) s += enemy_feats[(size_t)(n*NE_ + ei)*EDIM_ + lane];
            a_lds[w][1024 + lane] = s;
        } else if (lane < 16) {
            const int p = lane - 8;
            float s = 0.f;
            for (int ai = 0; ai < NAL_; ai++) s += ally_feats[(size_t)(n*NAL_ + ai)*ADIM_ + p];
            a_lds[w][1032 + p] = s;
        }

        float e = fc1_own_b[lane];
        const float* ow = own_feats + (size_t)n*OWN_;
#pragma unroll
        for (int j = 0; j < OWN_; j++) e = fmaf(ow[j], ws[FC1T_OFF + j*64 + lane], e);
        e += agent_emb[agent_idx[n]*64 + lane];
        e += action_emb[last_act[n]*64 + lane];
        embo = e;

        hin_lds[w][lane] = hidden_state[(size_t)n*64 + lane];
    }
    __syncthreads();

    // ================= Phase 2: folded dot, K-split, 20-row pipelined =======
    {
        float accA[4], accB[4];
#pragma unroll
        for (int nn = 0; nn < 4; nn++) { accA[nn] = (nn == w) ? embo : 0.f; accB[nn] = 0.f; }

        const int r0 = w * 260;
        const float* pw = ws + WBIG_OFF + (size_t)r0*64 + lane;
        float cur[20];
#pragma unroll
        for (int g = 0; g < 20; ++g) cur[g] = pw[g*64];
        pw += 20*64;

        int base = r0;
        for (int grp = 0; grp < 13; ++grp) {
            float nxt[20];
            if (grp < 12) {
#pragma unroll
                for (int g = 0; g < 20; ++g) nxt[g] = pw[g*64];
                pw += 20*64;
            }
#pragma unroll
            for (int nn = 0; nn < 4; ++nn) {
#pragma unroll
                for (int q = 0; q < 5; ++q) {
                    const float4 aa = *(const float4*)&a_lds[nn][base + q*4];
                    if (q & 1) {
                        accB[nn] = fmaf(aa.x, cur[q*4+0], accB[nn]);
                        accB[nn] = fmaf(aa.y, cur[q*4+1], accB[nn]);
                        accB[nn] = fmaf(aa.z, cur[q*4+2], accB[nn]);
                        accB[nn] = fmaf(aa.w, cur[q*4+3], accB[nn]);
                    } else {
                        accA[nn] = fmaf(aa.x, cur[q*4+0], accA[nn]);
                        accA[nn] = fmaf(aa.y, cur[q*4+1], accA[nn]);
                        accA[nn] = fmaf(aa.z, cur[q*4+2], accA[nn]);
                        accA[nn] = fmaf(aa.w, cur[q*4+3], accA[nn]);
                    }
                }
            }
            if (grp < 12) {
#pragma unroll
                for (int g = 0; g < 20; ++g) cur[g] = nxt[g];
            }
            base += 20;
        }
#pragma unroll
        for (int nn = 0; nn < 4; nn++) pemb[w][nn][lane] = accA[nn] + accB[nn];
    }
    __syncthreads();

    // finalize emb for agent w, write x
    {
        const float emb = pemb[0][w][lane] + pemb[1][w][lane]
                        + pemb[2][w][lane] + pemb[3][w][lane];
        x_lds[w][lane] = fmaxf(emb, 0.f);
    }
    __syncthreads();

    // ================= GRU: lane = (agent, unit16), block-shared weights ====
    {
        const int ag = lane >> 4;
        const int k  = (w << 4) + (lane & 15);
        float gr = gru_b_ih[k], gz = gru_b_ih[64 + k], gn = gru_b_ih[128 + k];
        float hr = gru_b_hh[k], hz = gru_b_hh[64 + k], hn = gru_b_hh[128 + k];
        const float* IHT = ws + IHT_OFF;
        const float* HHT = ws + HHT_OFF;
#pragma unroll 4
        for (int j = 0; j < 64; j++) {
            const float xj = x_lds[ag][j];
            const float hj = hin_lds[ag][j];
            gr = fmaf(xj, IHT[j*192 + k],       gr);
            gz = fmaf(xj, IHT[j*192 + 64 + k],  gz);
            gn = fmaf(xj, IHT[j*192 + 128 + k], gn);
            hr = fmaf(hj, HHT[j*192 + k],       hr);
            hz = fmaf(hj, HHT[j*192 + 64 + k],  hz);
            hn = fmaf(hj, HHT[j*192 + 128 + k], hn);
        }
        const float r = 1.f / (1.f + expf(-(gr + hr)));
        const float z = 1.f / (1.f + expf(-(gz + hz)));
        const float t = tanhf(gn + r * hn);
        const float hp = hin_lds[ag][k];
        hh_lds[ag][k] = (1.f - z) * t + z * hp;
    }
    __syncthreads();

    // ================= Epilogue for agent w: batched reductions =============
    {
        const float hh = hh_lds[w][lane];

        float prods[18];
#pragma unroll
        for (int l = 0; l < 6; l++) prods[l] = hh * fc2_w[l*64 + lane];
        prods[6] = hh * ws[BB_OFF + lane];

        // vv = Wc.hh + wb  (transposed WCT2[k][h'], float4)
        float vv = ws[WB_OFF + lane];
        const float* wct = ws + WCT2_OFF + lane*64;
#pragma unroll
        for (int j4 = 0; j4 < 64; j4 += 4) {
            const float4 hh4 = *(const float4*)&hh_lds[w][j4];
            const float4 wv  = *(const float4*)(wct + j4);
            vv = fmaf(hh4.x, wv.x, vv);
            vv = fmaf(hh4.y, wv.y, vv);
            vv = fmaf(hh4.z, wv.z, vv);
            vv = fmaf(hh4.w, wv.w, vv);
        }

#pragma unroll
        for (int ei = 0; ei < NE_; ei++) prods[7 + ei] = vv * h_e[ei];

#pragma unroll
        for (int i = 0; i < 18; i++) prods[i] = wave_red(prods[i]);

        if (lane == 0) {
            float* o = out + (size_t)n*17;
            const float sn = prods[6] + ws[CC_OFF];
#pragma unroll
            for (int l = 0; l < 6; l++) o[l] = prods[l] + fc2_b[l];
#pragma unroll
            for (int ei = 0; ei < NE_; ei++) o[6 + ei] = prods[7 + ei] + sn;
        }
    }
}

extern "C" void kernel_launch(void* const* d_in, const int* in_sizes, int n_in,
                              void* d_out, int out_size, void* d_ws, size_t ws_size,
                              hipStream_t stream)
{
    const float* own_feats   = (const float*)d_in[0];
    const float* enemy_feats = (const float*)d_in[1];
    const float* ally_feats  = (const float*)d_in[2];
    const float* hidden      = (const float*)d_in[3];
    const int*   agent_idx   = (const int*)d_in[4];
    const int*   last_act    = (const int*)d_in[5];
    const float* fc1_own_w   = (const float*)d_in[6];
    const float* fc1_own_b   = (const float*)d_in[7];
    const float* agent_emb   = (const float*)d_in[8];
    const float* action_emb  = (const float*)d_in[9];
    const float* he_w1       = (const float*)d_in[10];
    const float* he_b1       = (const float*)d_in[11];
    const float* he_w2       = (const float*)d_in[12];
    const float* he_b2       = (const float*)d_in[13];
    const float* ha_w1       = (const float*)d_in[14];
    const float* ha_b1       = (const float*)d_in[15];
    const float* ha_w2       = (const float*)d_in[16];
    const float* ha_b2       = (const float*)d_in[17];
    const float* merge_in_w  = (const float*)d_in[18];
    const float* gru_w_ih    = (const float*)d_in[19];
    const float* gru_w_hh    = (const float*)d_in[20];
    const float* gru_b_ih    = (const float*)d_in[21];
    const float* gru_b_hh    = (const float*)d_in[22];
    const float* fc2_w       = (const float*)d_in[23];
    const float* fc2_b       = (const float*)d_in[24];
    const float* merge_out_w = (const float*)d_in[25];
    float* out = (float*)d_out;
    float* ws  = (float*)d_ws;

    hipLaunchKernelGGL(prep_kernel, dim3(377), dim3(256), 0, stream,
                       fc1_own_w, he_w2, he_b2, ha_w2, ha_b2, merge_in_w,
                       gru_w_ih, gru_w_hh, merge_out_w, ws);
    hipLaunchKernelGGL(main_kernel, dim3(NTOT_/4), dim3(256), 0, stream,
                       own_feats, enemy_feats, ally_feats, hidden, agent_idx, last_act,
                       fc1_own_b, agent_emb, action_emb, he_w1, he_b1, ha_w1, ha_b1,
                       fc2_w, fc2_b, gru_b_ih, gru_b_hh, ws, out);
}

// Round 5
// 62.045 us; speedup vs baseline: 1.3119x; 1.0813x over previous
//
#include <hip/hip_runtime.h>
#include <hip/hip_bf16.h>
#include <math.h>

// Problem constants
#define BS_    512
#define NA_    10
#define NE_    11
#define NAL_   9
#define H_     64
#define HEADS_ 4
#define EDIM_  8
#define ADIM_  8
#define OWN_   14
#define HYP_   64
#define NTOT_  (BS_*NA_)   // 5120

// ws layout:
//   ushort region [0, 67584): Wpack[w][ks][lane][j] bf16 B-fragments (4 x 33 x 64 x 8)
//   float offsets below (1 float = 2 ushorts):
#define WPACK_US  67584     // ushort count = 33792 floats
#define WCT2_OFF  33792     // [64][64]  WCT2[k][h']
#define WB_OFF    37888     // [64]
#define BB_OFF    37952     // [64]
#define CC_OFF    38016     // [1]
#define FC1T_OFF  38080     // [14][64]
#define IHT_OFF   38976     // [64][192]
#define HHT_OFF   51264     // [64][192]
#define WS_FLOATS 63552

typedef __attribute__((ext_vector_type(8))) short short8_t;
typedef __attribute__((ext_vector_type(4))) float f32x4;

__global__ __launch_bounds__(256) void prep_kernel(
    const float* __restrict__ fc1_own_w,
    const float* __restrict__ he_w2, const float* __restrict__ he_b2,
    const float* __restrict__ ha_w2, const float* __restrict__ ha_b2,
    const float* __restrict__ merge_in_w,
    const float* __restrict__ gru_w_ih, const float* __restrict__ gru_w_hh,
    const float* __restrict__ merge_out_w,
    float* __restrict__ ws)
{
    const int tid = blockIdx.x * blockDim.x + threadIdx.x;

    float wo0, wo1, wo2, wo3;
    {
        float e0 = expf(merge_out_w[0]), e1 = expf(merge_out_w[1]);
        float e2 = expf(merge_out_w[2]), e3 = expf(merge_out_w[3]);
        float inv = 1.0f / (e0 + e1 + e2 + e3);
        wo0 = e0*inv; wo1 = e1*inv; wo2 = e2*inv; wo3 = e3*inv;
    }

    if (tid < 67584) {
        // Wpack[w][ks][l][j] = bf16( WBIG[idx = ks*32 + (l>>4)*8 + j][col = w*16 + (l&15)] )
        int t = tid;
        const int j  = t & 7;  t >>= 3;
        const int l  = t & 63; t >>= 6;
        const int ks = t % 33;
        const int w  = t / 33;
        const int idx = ks*32 + ((l >> 4) << 3) + j;
        const int col = (w << 4) + (l & 15);
        float v = 0.f;
        if (idx < 1040) {
            const float e0 = expf(merge_in_w[0*64 + col]), e1 = expf(merge_in_w[1*64 + col]);
            const float e2 = expf(merge_in_w[2*64 + col]), e3 = expf(merge_in_w[3*64 + col]);
            const float inv = 1.0f / (e0 + e1 + e2 + e3);
            const float wi[4] = { e0*inv, e1*inv, e2*inv, e3*inv };
            if (idx < 512) {
                const int e = idx >> 6, kk = idx & 63;
#pragma unroll
                for (int hd = 0; hd < 4; hd++)
                    v += wi[hd] * he_w2[(e*256 + hd*64 + col)*64 + kk];
            } else if (idx < 1024) {
                const int e = (idx - 512) >> 6, kk = idx & 63;
#pragma unroll
                for (int hd = 0; hd < 4; hd++)
                    v += wi[hd] * ha_w2[(e*256 + hd*64 + col)*64 + kk];
            } else if (idx < 1032) {
                const int e = idx - 1024;
#pragma unroll
                for (int hd = 0; hd < 4; hd++)
                    v += wi[hd] * he_b2[e*256 + hd*64 + col];
            } else {
                const int e = idx - 1032;
#pragma unroll
                for (int hd = 0; hd < 4; hd++)
                    v += wi[hd] * ha_b2[e*256 + hd*64 + col];
            }
        }
        unsigned u = __float_as_uint(v);
        u += 0x7fffu + ((u >> 16) & 1u);          // RNE to bf16
        ((unsigned short*)ws)[tid] = (unsigned short)(u >> 16);
    } else if (tid < 71680) {
        const int t = tid - 67584;
        const int k = t >> 6, hp = t & 63;
        float v = wo0 * he_w2[(2048 + 0*64 + hp)*64 + k]
                + wo1 * he_w2[(2048 + 1*64 + hp)*64 + k]
                + wo2 * he_w2[(2048 + 2*64 + hp)*64 + k]
                + wo3 * he_w2[(2048 + 3*64 + hp)*64 + k];
        ws[WCT2_OFF + t] = v;
    } else if (tid < 71744) {
        const int k = tid - 71680;
        float v = wo0*he_w2[(2304+0)*64 + k] + wo1*he_w2[(2304+1)*64 + k]
                + wo2*he_w2[(2304+2)*64 + k] + wo3*he_w2[(2304+3)*64 + k];
        ws[WB_OFF + k] = v;
    } else if (tid < 71808) {
        const int hp = tid - 71744;
        float v = wo0*he_b2[2048 + 0*64 + hp] + wo1*he_b2[2048 + 1*64 + hp]
                + wo2*he_b2[2048 + 2*64 + hp] + wo3*he_b2[2048 + 3*64 + hp];
        ws[BB_OFF + hp] = v;
    } else if (tid == 71808) {
        ws[CC_OFF] = wo0*he_b2[2304] + wo1*he_b2[2305] + wo2*he_b2[2306] + wo3*he_b2[2307];
    } else if (tid < 71872) {
        // pad
    } else if (tid < 72768) {
        const int t = tid - 71872; const int j = t >> 6, hp = t & 63;
        ws[FC1T_OFF + t] = fc1_own_w[hp*OWN_ + j];
    } else if (tid < 85056) {
        const int t = tid - 72768; const int j = t / 192, g = t % 192;
        ws[IHT_OFF + t] = gru_w_ih[g*64 + j];
    } else if (tid < 97344) {
        const int t = tid - 85056; const int j = t / 192, g = t % 192;
        ws[HHT_OFF + t] = gru_w_hh[g*64 + j];
    }
}

__device__ __forceinline__ float wave_red(float v) {
#pragma unroll
    for (int off = 32; off; off >>= 1) v += __shfl_xor(v, off);
    return v;
}

__global__ __launch_bounds__(256) void main_kernel(
    const float* __restrict__ own_feats,
    const float* __restrict__ enemy_feats,
    const float* __restrict__ ally_feats,
    const float* __restrict__ hidden_state,
    const int*   __restrict__ agent_idx,
    const int*   __restrict__ last_act,
    const float* __restrict__ fc1_own_b,
    const float* __restrict__ agent_emb,
    const float* __restrict__ action_emb,
    const float* __restrict__ he_w1,
    const float* __restrict__ he_b1,
    const float* __restrict__ ha_w1,
    const float* __restrict__ ha_b1,
    const float* __restrict__ fc2_w,
    const float* __restrict__ fc2_b,
    const float* __restrict__ gru_b_ih,
    const float* __restrict__ gru_b_hh,
    const float* __restrict__ ws,
    float* __restrict__ out)
{
    const int tid  = threadIdx.x;
    const int w    = tid >> 6;        // wave id 0..3 == agent slot
    const int lane = tid & 63;
    const int n    = blockIdx.x * 4 + w;

    // A-fragments (bf16) for MFMA: ldsA[ks][fl][j], 33*64*8 ushorts
    __shared__ __align__(16) unsigned short ldsA[16896];
    __shared__ float pembM[4][64];
    __shared__ float x_lds[4][68];
    __shared__ float hin_lds[4][68];
    __shared__ float hh_lds[4][68];

    // zero ldsA (rows 4..15 of each fragment tile must be 0)
    {
        unsigned* z = (unsigned*)ldsA;
        for (int i = tid; i < 8448; i += 256) z[i] = 0u;
    }
    __syncthreads();

    // ================= Phase 1: per-agent activations (wave = agent) ========
    float h_e[NE_];
    float embo;
    {
        const float4 w1a  = *(const float4*)(he_w1 + lane*8);
        const float4 w1b  = *(const float4*)(he_w1 + lane*8 + 4);
        const float  hb1  = he_b1[lane];

        float ps[8] = {0,0,0,0,0,0,0,0};
#pragma unroll
        for (int ei = 0; ei < NE_; ei++) {
            const float* ef = enemy_feats + (size_t)(n*NE_ + ei)*EDIM_;
            const float4 e0 = *(const float4*)ef;
            const float4 e1 = *(const float4*)(ef + 4);
            float h = hb1;
            h = fmaf(e0.x, w1a.x, h); h = fmaf(e0.y, w1a.y, h);
            h = fmaf(e0.z, w1a.z, h); h = fmaf(e0.w, w1a.w, h);
            h = fmaf(e1.x, w1b.x, h); h = fmaf(e1.y, w1b.y, h);
            h = fmaf(e1.z, w1b.z, h); h = fmaf(e1.w, w1b.w, h);
            h = fmaxf(h, 0.f);
            h_e[ei] = h;
            ps[0] = fmaf(e0.x, h, ps[0]); ps[1] = fmaf(e0.y, h, ps[1]);
            ps[2] = fmaf(e0.z, h, ps[2]); ps[3] = fmaf(e0.w, h, ps[3]);
            ps[4] = fmaf(e1.x, h, ps[4]); ps[5] = fmaf(e1.y, h, ps[5]);
            ps[6] = fmaf(e1.z, h, ps[6]); ps[7] = fmaf(e1.w, h, ps[7]);
        }

        const float4 wa1a = *(const float4*)(ha_w1 + lane*8);
        const float4 wa1b = *(const float4*)(ha_w1 + lane*8 + 4);
        const float  hba1 = ha_b1[lane];
        float pa[8] = {0,0,0,0,0,0,0,0};
#pragma unroll
        for (int ai = 0; ai < NAL_; ai++) {
            const float* af = ally_feats + (size_t)(n*NAL_ + ai)*ADIM_;
            const float4 a0 = *(const float4*)af;
            const float4 a1 = *(const float4*)(af + 4);
            float h = hba1;
            h = fmaf(a0.x, wa1a.x, h); h = fmaf(a0.y, wa1a.y, h);
            h = fmaf(a0.z, wa1a.z, h); h = fmaf(a0.w, wa1a.w, h);
            h = fmaf(a1.x, wa1b.x, h); h = fmaf(a1.y, wa1b.y, h);
            h = fmaf(a1.z, wa1b.z, h); h = fmaf(a1.w, wa1b.w, h);
            h = fmaxf(h, 0.f);
            pa[0] = fmaf(a0.x, h, pa[0]); pa[1] = fmaf(a0.y, h, pa[1]);
            pa[2] = fmaf(a0.z, h, pa[2]); pa[3] = fmaf(a0.w, h, pa[3]);
            pa[4] = fmaf(a1.x, h, pa[4]); pa[5] = fmaf(a1.y, h, pa[5]);
            pa[6] = fmaf(a1.z, h, pa[6]); pa[7] = fmaf(a1.w, h, pa[7]);
        }

        // scatter a-values into A-fragment layout (bf16)
        // value (agent=w, idx): ks=idx>>5, sub=idx&31, fl = w + 16*(sub>>3), j = sub&7
        // ushort address = ks*512 + fl*8 + j
        auto scat = [&](int idx, float v) {
            unsigned u = __float_as_uint(v);
            u += 0x7fffu + ((u >> 16) & 1u);
            const int sub = idx & 31;
            const int addr = ((idx >> 5) << 9) + ((w + ((sub >> 3) << 4)) << 3) + (sub & 7);
            ldsA[addr] = (unsigned short)(u >> 16);
        };
#pragma unroll
        for (int e = 0; e < 8; e++) scat(e*64 + lane, ps[e]);
#pragma unroll
        for (int e = 0; e < 8; e++) scat(512 + e*64 + lane, pa[e]);

        if (lane < 8) {
            float s = 0.f;
            for (int ei = 0; ei < NE_; ei++) s += enemy_feats[(size_t)(n*NE_ + ei)*EDIM_ + lane];
            scat(1024 + lane, s);
        } else if (lane < 16) {
            const int p = lane - 8;
            float s = 0.f;
            for (int ai = 0; ai < NAL_; ai++) s += ally_feats[(size_t)(n*NAL_ + ai)*ADIM_ + p];
            scat(1032 + p, s);
        }

        float e = fc1_own_b[lane];
        const float* ow = own_feats + (size_t)n*OWN_;
#pragma unroll
        for (int j = 0; j < OWN_; j++) e = fmaf(ow[j], ws[FC1T_OFF + j*64 + lane], e);
        e += agent_emb[agent_idx[n]*64 + lane];
        e += action_emb[last_act[n]*64 + lane];
        embo = e;

        hin_lds[w][lane] = hidden_state[(size_t)n*64 + lane];
    }
    __syncthreads();

    // ================= Phase 2: MFMA  emb[4x64] = A[4x1056] * W[1056x64] ====
    {
        f32x4 acc = {0.f, 0.f, 0.f, 0.f};
        const unsigned short* wpw = (const unsigned short*)ws + ((w * 33) << 9);
#pragma unroll 8
        for (int ks = 0; ks < 33; ++ks) {
            const short8_t afr = *(const short8_t*)&ldsA[(ks << 9) + (lane << 3)];
            const short8_t bfr = *(const short8_t*)&wpw[(ks << 9) + (lane << 3)];
            acc = __builtin_amdgcn_mfma_f32_16x16x32_bf16(afr, bfr, acc, 0, 0, 0);
        }
        // D layout: lane l, reg r -> row=(l>>4)*4+r (agent, rows 0..3 valid), col=l&15
        if (lane < 16) {
#pragma unroll
            for (int r = 0; r < 4; ++r) pembM[r][(w << 4) + lane] = acc[r];
        }
    }
    __syncthreads();

    // finalize emb for agent w, write x
    x_lds[w][lane] = fmaxf(embo + pembM[w][lane], 0.f);
    __syncthreads();

    // ================= GRU: lane = (agent, unit16), block-shared weights ====
    {
        const int ag = lane >> 4;
        const int k  = (w << 4) + (lane & 15);
        float gr = gru_b_ih[k], gz = gru_b_ih[64 + k], gn = gru_b_ih[128 + k];
        float hr = gru_b_hh[k], hz = gru_b_hh[64 + k], hn = gru_b_hh[128 + k];
        const float* IHT = ws + IHT_OFF;
        const float* HHT = ws + HHT_OFF;
#pragma unroll 4
        for (int j = 0; j < 64; j++) {
            const float xj = x_lds[ag][j];
            const float hj = hin_lds[ag][j];
            gr = fmaf(xj, IHT[j*192 + k],       gr);
            gz = fmaf(xj, IHT[j*192 + 64 + k],  gz);
            gn = fmaf(xj, IHT[j*192 + 128 + k], gn);
            hr = fmaf(hj, HHT[j*192 + k],       hr);
            hz = fmaf(hj, HHT[j*192 + 64 + k],  hz);
            hn = fmaf(hj, HHT[j*192 + 128 + k], hn);
        }
        const float r = 1.f / (1.f + expf(-(gr + hr)));
        const float z = 1.f / (1.f + expf(-(gz + hz)));
        const float t = tanhf(gn + r * hn);
        const float hp = hin_lds[ag][k];
        hh_lds[ag][k] = (1.f - z) * t + z * hp;
    }
    __syncthreads();

    // ================= Epilogue for agent w: batched reductions =============
    {
        const float hh = hh_lds[w][lane];

        float prods[18];
#pragma unroll
        for (int l = 0; l < 6; l++) prods[l] = hh * fc2_w[l*64 + lane];
        prods[6] = hh * ws[BB_OFF + lane];

        // vv = Wc.hh + wb  (transposed WCT2[k][h'], float4)
        float vv = ws[WB_OFF + lane];
        const float* wct = ws + WCT2_OFF + lane*64;
#pragma unroll
        for (int j4 = 0; j4 < 64; j4 += 4) {
            const float4 hh4 = *(const float4*)&hh_lds[w][j4];
            const float4 wv  = *(const float4*)(wct + j4);
            vv = fmaf(hh4.x, wv.x, vv);
            vv = fmaf(hh4.y, wv.y, vv);
            vv = fmaf(hh4.z, wv.z, vv);
            vv = fmaf(hh4.w, wv.w, vv);
        }

#pragma unroll
        for (int ei = 0; ei < NE_; ei++) prods[7 + ei] = vv * h_e[ei];

#pragma unroll
        for (int i = 0; i < 18; i++) prods[i] = wave_red(prods[i]);

        if (lane == 0) {
            float* o = out + (size_t)n*17;
            const float sn = prods[6] + ws[CC_OFF];
#pragma unroll
            for (int l = 0; l < 6; l++) o[l] = prods[l] + fc2_b[l];
#pragma unroll
            for (int ei = 0; ei < NE_; ei++) o[6 + ei] = prods[7 + ei] + sn;
        }
    }
}

extern "C" void kernel_launch(void* const* d_in, const int* in_sizes, int n_in,
                              void* d_out, int out_size, void* d_ws, size_t ws_size,
                              hipStream_t stream)
{
    const float* own_feats   = (const float*)d_in[0];
    const float* enemy_feats = (const float*)d_in[1];
    const float* ally_feats  = (const float*)d_in[2];
    const float* hidden      = (const float*)d_in[3];
    const int*   agent_idx   = (const int*)d_in[4];
    const int*   last_act    = (const int*)d_in[5];
    const float* fc1_own_w   = (const float*)d_in[6];
    const float* fc1_own_b   = (const float*)d_in[7];
    const float* agent_emb   = (const float*)d_in[8];
    const float* action_emb  = (const float*)d_in[9];
    const float* he_w1       = (const float*)d_in[10];
    const float* he_b1       = (const float*)d_in[11];
    const float* he_w2       = (const float*)d_in[12];
    const float* he_b2       = (const float*)d_in[13];
    const float* ha_w1       = (const float*)d_in[14];
    const float* ha_b1       = (const float*)d_in[15];
    const float* ha_w2       = (const float*)d_in[16];
    const float* ha_b2       = (const float*)d_in[17];
    const float* merge_in_w  = (const float*)d_in[18];
    const float* gru_w_ih    = (const float*)d_in[19];
    const float* gru_w_hh    = (const float*)d_in[20];
    const float* gru_b_ih    = (const float*)d_in[21];
    const float* gru_b_hh    = (const float*)d_in[22];
    const float* fc2_w       = (const float*)d_in[23];
    const float* fc2_b       = (const float*)d_in[24];
    const float* merge_out_w = (const float*)d_in[25];
    float* out = (float*)d_out;
    float* ws  = (float*)d_ws;

    hipLaunchKernelGGL(prep_kernel, dim3(381), dim3(256), 0, stream,
                       fc1_own_w, he_w2, he_b2, ha_w2, ha_b2, merge_in_w,
                       gru_w_ih, gru_w_hh, merge_out_w, ws);
    hipLaunchKernelGGL(main_kernel, dim3(NTOT_/4), dim3(256), 0, stream,
                       own_feats, enemy_feats, ally_feats, hidden, agent_idx, last_act,
                       fc1_own_b, agent_emb, action_emb, he_w1, he_b1, ha_w1, ha_b1,
                       fc2_w, fc2_b, gru_b_ih, gru_b_hh, ws, out);
}

// Round 6
// 49.639 us; speedup vs baseline: 1.6398x; 1.2499x over previous
//
#include <hip/hip_runtime.h>
#include <hip/hip_bf16.h>
#include <math.h>

// Problem constants
#define BS_    512
#define NA_    10
#define NE_    11
#define NAL_   9
#define H_     64
#define HEADS_ 4
#define EDIM_  8
#define ADIM_  8
#define OWN_   14
#define HYP_   64
#define NTOT_  (BS_*NA_)   // 5120

// ws layout:
//   ushort [0, 67584):        phase2 Wpack[w][ks][fl][j] bf16 (4 x 33 x 64 x 8)
//   ushort [67584, 100352):   GRU Wpack[T][kstep][fl][j] bf16 (16 x 4 x 64 x 8)
//   float offsets (1 float = 2 ushorts):
#define WGRU_US   67584
#define WCT2_OFF  50176     // [64][64]  WCT2[k][h']
#define WB_OFF    54272     // [64]
#define BB_OFF    54336     // [64]
#define CC_OFF    54400     // [1]
#define B4_OFF    54464     // [256] gru bias table (rz combined, i_n, h_n)
#define FC1T_OFF  54720     // [14][64]
#define WS_FLOATS 55616

typedef __attribute__((ext_vector_type(8))) short short8_t;
typedef __attribute__((ext_vector_type(4))) float f32x4;

// bank-conflict swizzle for ldsA (ushort index): XOR fl-bits 0..1 with fl-bits 4..5
__device__ __forceinline__ int swz(int us) { return us ^ (((us >> 7) & 3) << 3); }

__device__ __forceinline__ unsigned short to_bf16(float v) {
    unsigned u = __float_as_uint(v);
    u += 0x7fffu + ((u >> 16) & 1u);
    return (unsigned short)(u >> 16);
}

__global__ __launch_bounds__(256) void prep_kernel(
    const float* __restrict__ fc1_own_w,
    const float* __restrict__ he_w2, const float* __restrict__ he_b2,
    const float* __restrict__ ha_w2, const float* __restrict__ ha_b2,
    const float* __restrict__ merge_in_w,
    const float* __restrict__ gru_w_ih, const float* __restrict__ gru_w_hh,
    const float* __restrict__ gru_b_ih, const float* __restrict__ gru_b_hh,
    const float* __restrict__ merge_out_w,
    float* __restrict__ ws)
{
    const int tid = blockIdx.x * blockDim.x + threadIdx.x;

    float wo0, wo1, wo2, wo3;
    {
        float e0 = expf(merge_out_w[0]), e1 = expf(merge_out_w[1]);
        float e2 = expf(merge_out_w[2]), e3 = expf(merge_out_w[3]);
        float inv = 1.0f / (e0 + e1 + e2 + e3);
        wo0 = e0*inv; wo1 = e1*inv; wo2 = e2*inv; wo3 = e3*inv;
    }

    if (tid < 67584) {
        // phase-2 Wpack[w][ks][l][j] = bf16( WBIG[idx=ks*32+(l>>4)*8+j][col=w*16+(l&15)] )
        int t = tid;
        const int j  = t & 7;  t >>= 3;
        const int l  = t & 63; t >>= 6;
        const int ks = t % 33;
        const int w  = t / 33;
        const int idx = ks*32 + ((l >> 4) << 3) + j;
        const int col = (w << 4) + (l & 15);
        float v = 0.f;
        if (idx < 1040) {
            const float e0 = expf(merge_in_w[0*64 + col]), e1 = expf(merge_in_w[1*64 + col]);
            const float e2 = expf(merge_in_w[2*64 + col]), e3 = expf(merge_in_w[3*64 + col]);
            const float inv = 1.0f / (e0 + e1 + e2 + e3);
            const float wi[4] = { e0*inv, e1*inv, e2*inv, e3*inv };
            if (idx < 512) {
                const int e = idx >> 6, kk = idx & 63;
#pragma unroll
                for (int hd = 0; hd < 4; hd++)
                    v += wi[hd] * he_w2[(e*256 + hd*64 + col)*64 + kk];
            } else if (idx < 1024) {
                const int e = (idx - 512) >> 6, kk = idx & 63;
#pragma unroll
                for (int hd = 0; hd < 4; hd++)
                    v += wi[hd] * ha_w2[(e*256 + hd*64 + col)*64 + kk];
            } else if (idx < 1032) {
                const int e = idx - 1024;
#pragma unroll
                for (int hd = 0; hd < 4; hd++)
                    v += wi[hd] * he_b2[e*256 + hd*64 + col];
            } else {
                const int e = idx - 1032;
#pragma unroll
                for (int hd = 0; hd < 4; hd++)
                    v += wi[hd] * ha_b2[e*256 + hd*64 + col];
            }
        }
        ((unsigned short*)ws)[tid] = to_bf16(v);
    } else if (tid < 100352) {
        // GRU Wpack[T][kstep][fl][j]: W[k][c], c: [r | z | i_n | h_n]
        const int t = tid - 67584;
        const int j  = t & 7;
        const int fl = (t >> 3) & 63;
        const int kstep = (t >> 9) & 3;
        const int T  = t >> 11;                 // 0..15
        const int k  = kstep*32 + ((fl >> 4) << 3) + j;   // 0..127
        const int c  = T*16 + (fl & 15);        // 0..255
        const int g  = c >> 6;
        const int u  = c & 63;
        float v;
        if (g == 0)      v = (k < 64) ? gru_w_ih[u*64 + k]        : gru_w_hh[u*64 + (k-64)];
        else if (g == 1) v = (k < 64) ? gru_w_ih[(64+u)*64 + k]   : gru_w_hh[(64+u)*64 + (k-64)];
        else if (g == 2) v = (k < 64) ? gru_w_ih[(128+u)*64 + k]  : 0.f;
        else             v = (k < 64) ? 0.f                       : gru_w_hh[(128+u)*64 + (k-64)];
        ((unsigned short*)ws)[WGRU_US + t] = to_bf16(v);
    } else if (tid < 104448) {
        const int t = tid - 100352;
        const int k = t >> 6, hp = t & 63;
        float v = wo0 * he_w2[(2048 + 0*64 + hp)*64 + k]
                + wo1 * he_w2[(2048 + 1*64 + hp)*64 + k]
                + wo2 * he_w2[(2048 + 2*64 + hp)*64 + k]
                + wo3 * he_w2[(2048 + 3*64 + hp)*64 + k];
        ws[WCT2_OFF + t] = v;
    } else if (tid < 104512) {
        const int k = tid - 104448;
        float v = wo0*he_w2[(2304+0)*64 + k] + wo1*he_w2[(2304+1)*64 + k]
                + wo2*he_w2[(2304+2)*64 + k] + wo3*he_w2[(2304+3)*64 + k];
        ws[WB_OFF + k] = v;
    } else if (tid < 104576) {
        const int hp = tid - 104512;
        float v = wo0*he_b2[2048 + 0*64 + hp] + wo1*he_b2[2048 + 1*64 + hp]
                + wo2*he_b2[2048 + 2*64 + hp] + wo3*he_b2[2048 + 3*64 + hp];
        ws[BB_OFF + hp] = v;
    } else if (tid == 104576) {
        ws[CC_OFF] = wo0*he_b2[2304] + wo1*he_b2[2305] + wo2*he_b2[2306] + wo3*he_b2[2307];
    } else if (tid < 104640) {
        // pad
    } else if (tid < 104896) {
        const int c = tid - 104640;
        const int g = c >> 6, u = c & 63;
        float v;
        if (g == 0)      v = gru_b_ih[u]       + gru_b_hh[u];
        else if (g == 1) v = gru_b_ih[64 + u]  + gru_b_hh[64 + u];
        else if (g == 2) v = gru_b_ih[128 + u];
        else             v = gru_b_hh[128 + u];
        ws[B4_OFF + c] = v;
    } else if (tid < 105792) {
        const int t = tid - 104896; const int j = t >> 6, hp = t & 63;
        ws[FC1T_OFF + t] = fc1_own_w[hp*OWN_ + j];
    }
}

__device__ __forceinline__ float wave_red(float v) {
#pragma unroll
    for (int off = 32; off; off >>= 1) v += __shfl_xor(v, off);
    return v;
}

__global__ __launch_bounds__(256) void main_kernel(
    const float* __restrict__ own_feats,
    const float* __restrict__ enemy_feats,
    const float* __restrict__ ally_feats,
    const float* __restrict__ hidden_state,
    const int*   __restrict__ agent_idx,
    const int*   __restrict__ last_act,
    const float* __restrict__ fc1_own_b,
    const float* __restrict__ agent_emb,
    const float* __restrict__ action_emb,
    const float* __restrict__ he_w1,
    const float* __restrict__ he_b1,
    const float* __restrict__ ha_w1,
    const float* __restrict__ ha_b1,
    const float* __restrict__ fc2_w,
    const float* __restrict__ fc2_b,
    const float* __restrict__ ws,
    float* __restrict__ out)
{
    const int tid  = threadIdx.x;
    const int w    = tid >> 6;        // wave id 0..3 == agent slot
    const int lane = tid & 63;
    const int n    = blockIdx.x * 4 + w;

    // ldsA: phase-2 A-fragments [33][64][8]us; later: GRU A (us 0..2047) and
    // G gate matrix (floats at byte 8192, [4][260])
    __shared__ __align__(16) unsigned short ldsA[16896];
    __shared__ float pembM[4][64];
    __shared__ float hin_lds[4][68];
    __shared__ float hh_lds[4][68];

    // zero ldsA (rows 4..15 of each fragment tile must be 0)
    {
        unsigned* z = (unsigned*)ldsA;
        for (int i = tid; i < 8448; i += 256) z[i] = 0u;
    }
    __syncthreads();

    // ================= Phase 1: per-agent activations (wave = agent) ========
    float h_e[NE_];
    float embo, hin_reg;
    {
        const float4 w1a  = *(const float4*)(he_w1 + lane*8);
        const float4 w1b  = *(const float4*)(he_w1 + lane*8 + 4);
        const float  hb1  = he_b1[lane];

        float ps[8] = {0,0,0,0,0,0,0,0};
#pragma unroll
        for (int ei = 0; ei < NE_; ei++) {
            const float* ef = enemy_feats + (size_t)(n*NE_ + ei)*EDIM_;
            const float4 e0 = *(const float4*)ef;
            const float4 e1 = *(const float4*)(ef + 4);
            float h = hb1;
            h = fmaf(e0.x, w1a.x, h); h = fmaf(e0.y, w1a.y, h);
            h = fmaf(e0.z, w1a.z, h); h = fmaf(e0.w, w1a.w, h);
            h = fmaf(e1.x, w1b.x, h); h = fmaf(e1.y, w1b.y, h);
            h = fmaf(e1.z, w1b.z, h); h = fmaf(e1.w, w1b.w, h);
            h = fmaxf(h, 0.f);
            h_e[ei] = h;
            ps[0] = fmaf(e0.x, h, ps[0]); ps[1] = fmaf(e0.y, h, ps[1]);
            ps[2] = fmaf(e0.z, h, ps[2]); ps[3] = fmaf(e0.w, h, ps[3]);
            ps[4] = fmaf(e1.x, h, ps[4]); ps[5] = fmaf(e1.y, h, ps[5]);
            ps[6] = fmaf(e1.z, h, ps[6]); ps[7] = fmaf(e1.w, h, ps[7]);
        }

        const float4 wa1a = *(const float4*)(ha_w1 + lane*8);
        const float4 wa1b = *(const float4*)(ha_w1 + lane*8 + 4);
        const float  hba1 = ha_b1[lane];
        float pa[8] = {0,0,0,0,0,0,0,0};
#pragma unroll
        for (int ai = 0; ai < NAL_; ai++) {
            const float* af = ally_feats + (size_t)(n*NAL_ + ai)*ADIM_;
            const float4 a0 = *(const float4*)af;
            const float4 a1 = *(const float4*)(af + 4);
            float h = hba1;
            h = fmaf(a0.x, wa1a.x, h); h = fmaf(a0.y, wa1a.y, h);
            h = fmaf(a0.z, wa1a.z, h); h = fmaf(a0.w, wa1a.w, h);
            h = fmaf(a1.x, wa1b.x, h); h = fmaf(a1.y, wa1b.y, h);
            h = fmaf(a1.z, wa1b.z, h); h = fmaf(a1.w, wa1b.w, h);
            h = fmaxf(h, 0.f);
            pa[0] = fmaf(a0.x, h, pa[0]); pa[1] = fmaf(a0.y, h, pa[1]);
            pa[2] = fmaf(a0.z, h, pa[2]); pa[3] = fmaf(a0.w, h, pa[3]);
            pa[4] = fmaf(a1.x, h, pa[4]); pa[5] = fmaf(a1.y, h, pa[5]);
            pa[6] = fmaf(a1.z, h, pa[6]); pa[7] = fmaf(a1.w, h, pa[7]);
        }

        // scatter a-values into A-fragment layout (bf16, swizzled)
        auto scat = [&](int idx, float v) {
            const int sub = idx & 31;
            const int addr = ((idx >> 5) << 9) + ((w + ((sub >> 3) << 4)) << 3) + (sub & 7);
            ldsA[swz(addr)] = to_bf16(v);
        };
#pragma unroll
        for (int e = 0; e < 8; e++) scat(e*64 + lane, ps[e]);
#pragma unroll
        for (int e = 0; e < 8; e++) scat(512 + e*64 + lane, pa[e]);

        if (lane < 8) {
            float s = 0.f;
            for (int ei = 0; ei < NE_; ei++) s += enemy_feats[(size_t)(n*NE_ + ei)*EDIM_ + lane];
            scat(1024 + lane, s);
        } else if (lane < 16) {
            const int p = lane - 8;
            float s = 0.f;
            for (int ai = 0; ai < NAL_; ai++) s += ally_feats[(size_t)(n*NAL_ + ai)*ADIM_ + p];
            scat(1032 + p, s);
        }

        float e = fc1_own_b[lane];
        const float* ow = own_feats + (size_t)n*OWN_;
#pragma unroll
        for (int j = 0; j < OWN_; j++) e = fmaf(ow[j], ws[FC1T_OFF + j*64 + lane], e);
        e += agent_emb[agent_idx[n]*64 + lane];
        e += action_emb[last_act[n]*64 + lane];
        embo = e;

        hin_reg = hidden_state[(size_t)n*64 + lane];
        hin_lds[w][lane] = hin_reg;
    }
    __syncthreads();

    // ================= Phase 2: MFMA  emb[4x64] = A[4x1056] * W[1056x64] ====
    {
        f32x4 acc = {0.f, 0.f, 0.f, 0.f};
        const unsigned short* wpw = (const unsigned short*)ws + ((w * 33) << 9);
#pragma unroll 8
        for (int ks = 0; ks < 33; ++ks) {
            const short8_t afr = *(const short8_t*)&ldsA[swz((ks << 9) + (lane << 3))];
            const short8_t bfr = *(const short8_t*)&wpw[(ks << 9) + (lane << 3)];
            acc = __builtin_amdgcn_mfma_f32_16x16x32_bf16(afr, bfr, acc, 0, 0, 0);
        }
        if (lane < 16) {
#pragma unroll
            for (int r = 0; r < 4; ++r) pembM[r][(w << 4) + lane] = acc[r];
        }
    }
    __syncthreads();

    // ================= GRU stage A: scatter [x|h] bf16 into ldsA K-tiles 0..3
    {
        const float x = fmaxf(embo + pembM[w][lane], 0.f);
        auto scat2 = [&](int j, float v) {
            const int sub = j & 31;
            const int addr = ((j >> 5) << 9) + ((w + ((sub >> 3) << 4)) << 3) + (sub & 7);
            ldsA[swz(addr)] = to_bf16(v);
        };
        scat2(lane, x);
        scat2(64 + lane, hin_reg);
    }
    __syncthreads();

    // ================= GRU stage B: MFMA G[4x256] = [x|h][4x128] * Wgru =====
    {
        short8_t afr[4];
#pragma unroll
        for (int kstep = 0; kstep < 4; ++kstep)
            afr[kstep] = *(const short8_t*)&ldsA[swz((kstep << 9) + (lane << 3))];

        float* Gp = (float*)(ldsA + 4096);   // byte 8192, [4][260]
        const unsigned short* wg = (const unsigned short*)ws + WGRU_US;
#pragma unroll
        for (int tt = 0; tt < 4; ++tt) {
            const int T = (w << 2) + tt;
            const float b = ws[B4_OFF + (T << 4) + (lane & 15)];
            f32x4 acc = {b, b, b, b};
#pragma unroll
            for (int kstep = 0; kstep < 4; ++kstep) {
                const short8_t bfr = *(const short8_t*)&wg[(((T << 2) + kstep) << 9) + (lane << 3)];
                acc = __builtin_amdgcn_mfma_f32_16x16x32_bf16(afr[kstep], bfr, acc, 0, 0, 0);
            }
            if (lane < 16) {
#pragma unroll
                for (int r = 0; r < 4; ++r) Gp[r*260 + (T << 4) + lane] = acc[r];
            }
        }
    }
    __syncthreads();

    // ================= GRU stage C: gate nonlinearities =====================
    {
        const float* Gp = (const float*)(ldsA + 4096);
        const int ag = lane >> 4;
        const int k  = (w << 4) + (lane & 15);
        const float gr = Gp[ag*260 + k];
        const float gz = Gp[ag*260 + 64 + k];
        const float gi = Gp[ag*260 + 128 + k];
        const float gh = Gp[ag*260 + 192 + k];
        const float r = 1.f / (1.f + expf(-gr));
        const float z = 1.f / (1.f + expf(-gz));
        const float t = tanhf(gi + r * gh);
        hh_lds[ag][k] = (1.f - z) * t + z * hin_lds[ag][k];
    }
    __syncthreads();

    // ================= Epilogue for agent w: batched reductions =============
    {
        const float hh = hh_lds[w][lane];

        float prods[18];
#pragma unroll
        for (int l = 0; l < 6; l++) prods[l] = hh * fc2_w[l*64 + lane];
        prods[6] = hh * ws[BB_OFF + lane];

        float vv = ws[WB_OFF + lane];
        const float* wct = ws + WCT2_OFF + lane*64;
#pragma unroll
        for (int j4 = 0; j4 < 64; j4 += 4) {
            const float4 hh4 = *(const float4*)&hh_lds[w][j4];
            const float4 wv  = *(const float4*)(wct + j4);
            vv = fmaf(hh4.x, wv.x, vv);
            vv = fmaf(hh4.y, wv.y, vv);
            vv = fmaf(hh4.z, wv.z, vv);
            vv = fmaf(hh4.w, wv.w, vv);
        }

#pragma unroll
        for (int ei = 0; ei < NE_; ei++) prods[7 + ei] = vv * h_e[ei];

#pragma unroll
        for (int i = 0; i < 18; i++) prods[i] = wave_red(prods[i]);

        if (lane == 0) {
            float* o = out + (size_t)n*17;
            const float sn = prods[6] + ws[CC_OFF];
#pragma unroll
            for (int l = 0; l < 6; l++) o[l] = prods[l] + fc2_b[l];
#pragma unroll
            for (int ei = 0; ei < NE_; ei++) o[6 + ei] = prods[7 + ei] + sn;
        }
    }
}

extern "C" void kernel_launch(void* const* d_in, const int* in_sizes, int n_in,
                              void* d_out, int out_size, void* d_ws, size_t ws_size,
                              hipStream_t stream)
{
    const float* own_feats   = (const float*)d_in[0];
    const float* enemy_feats = (const float*)d_in[1];
    const float* ally_feats  = (const float*)d_in[2];
    const float* hidden      = (const float*)d_in[3];
    const int*   agent_idx   = (const int*)d_in[4];
    const int*   last_act    = (const int*)d_in[5];
    const float* fc1_own_w   = (const float*)d_in[6];
    const float* fc1_own_b   = (const float*)d_in[7];
    const float* agent_emb   = (const float*)d_in[8];
    const float* action_emb  = (const float*)d_in[9];
    const float* he_w1       = (const float*)d_in[10];
    const float* he_b1       = (const float*)d_in[11];
    const float* he_w2       = (const float*)d_in[12];
    const float* he_b2       = (const float*)d_in[13];
    const float* ha_w1       = (const float*)d_in[14];
    const float* ha_b1       = (const float*)d_in[15];
    const float* ha_w2       = (const float*)d_in[16];
    const float* ha_b2       = (const float*)d_in[17];
    const float* merge_in_w  = (const float*)d_in[18];
    const float* gru_w_ih    = (const float*)d_in[19];
    const float* gru_w_hh    = (const float*)d_in[20];
    const float* gru_b_ih    = (const float*)d_in[21];
    const float* gru_b_hh    = (const float*)d_in[22];
    const float* fc2_w       = (const float*)d_in[23];
    const float* fc2_b       = (const float*)d_in[24];
    const float* merge_out_w = (const float*)d_in[25];
    float* out = (float*)d_out;
    float* ws  = (float*)d_ws;

    hipLaunchKernelGGL(prep_kernel, dim3(414), dim3(256), 0, stream,
                       fc1_own_w, he_w2, he_b2, ha_w2, ha_b2, merge_in_w,
                       gru_w_ih, gru_w_hh, gru_b_ih, gru_b_hh, merge_out_w, ws);
    hipLaunchKernelGGL(main_kernel, dim3(NTOT_/4), dim3(256), 0, stream,
                       own_feats, enemy_feats, ally_feats, hidden, agent_idx, last_act,
                       fc1_own_b, agent_emb, action_emb, he_w1, he_b1, ha_w1, ha_b1,
                       fc2_w, fc2_b, ws, out);
}

// Round 7
// 47.174 us; speedup vs baseline: 1.7255x; 1.0523x over previous
//
#include <hip/hip_runtime.h>
#include <hip/hip_bf16.h>
#include <math.h>

// Problem constants
#define BS_    512
#define NA_    10
#define NE_    11
#define NAL_   9
#define H_     64
#define HEADS_ 4
#define EDIM_  8
#define ADIM_  8
#define OWN_   14
#define HYP_   64
#define NTOT_  (BS_*NA_)   // 5120

// ws layout:
//   ushort [0, 67584):        phase2 Wpack[w][ks][fl][j] bf16 (4 x 33 x 64 x 8), K-permuted
//   ushort [67584, 100352):   GRU Wpack[T][kstep][fl][j] bf16 (16 x 4 x 64 x 8), x|h interleaved
//   float offsets (1 float = 2 ushorts):
#define WGRU_US   67584
#define WCT2_OFF  50176     // [64][64]  WCT2[k][h']
#define WB_OFF    54272     // [64]
#define BB_OFF    54336     // [64]
#define CC_OFF    54400     // [1]
#define B4_OFF    54464     // [256] gru bias (r | z | i_n | h_n)
#define FC1T_OFF  54720     // [14][64]
#define WS_FLOATS 55616

typedef __attribute__((ext_vector_type(8))) short short8_t;
typedef __attribute__((ext_vector_type(4))) float f32x4;

__device__ __forceinline__ unsigned short to_bf16(float v) {
    unsigned u = __float_as_uint(v);
    u += 0x7fffu + ((u >> 16) & 1u);
    return (unsigned short)(u >> 16);
}
__device__ __forceinline__ unsigned pack2(float lo, float hi) {
    return ((unsigned)to_bf16(hi) << 16) | to_bf16(lo);
}

__global__ __launch_bounds__(256) void prep_kernel(
    const float* __restrict__ fc1_own_w,
    const float* __restrict__ he_w2, const float* __restrict__ he_b2,
    const float* __restrict__ ha_w2, const float* __restrict__ ha_b2,
    const float* __restrict__ merge_in_w,
    const float* __restrict__ gru_w_ih, const float* __restrict__ gru_w_hh,
    const float* __restrict__ gru_b_ih, const float* __restrict__ gru_b_hh,
    const float* __restrict__ merge_out_w,
    float* __restrict__ ws)
{
    const int tid = blockIdx.x * blockDim.x + threadIdx.x;

    float wo0, wo1, wo2, wo3;
    {
        float e0 = expf(merge_out_w[0]), e1 = expf(merge_out_w[1]);
        float e2 = expf(merge_out_w[2]), e3 = expf(merge_out_w[3]);
        float inv = 1.0f / (e0 + e1 + e2 + e3);
        wo0 = e0*inv; wo1 = e1*inv; wo2 = e2*inv; wo3 = e3*inv;
    }

    if (tid < 67584) {
        // phase-2 Wpack: fragment position (w,ks,l,j) -> k -> permuted source row idx
        int t = tid;
        const int j  = t & 7;  t >>= 3;
        const int l  = t & 63; t >>= 6;
        const int ks = t % 33;
        const int w  = t / 33;
        const int k  = ks*32 + ((l >> 4) << 3) + j;
        const int col = (w << 4) + (l & 15);
        // K-permutation: k<512: idx=(k&7)*64+(k>>3); 512..1023 same within block; else identity
        int idx;
        if (k < 512)       idx = ((k & 7) << 6) + (k >> 3);
        else if (k < 1024) idx = 512 + ((((k-512) & 7) << 6) + ((k-512) >> 3));
        else               idx = k;
        float v = 0.f;
        if (idx < 1040) {
            const float e0 = expf(merge_in_w[0*64 + col]), e1 = expf(merge_in_w[1*64 + col]);
            const float e2 = expf(merge_in_w[2*64 + col]), e3 = expf(merge_in_w[3*64 + col]);
            const float inv = 1.0f / (e0 + e1 + e2 + e3);
            const float wi[4] = { e0*inv, e1*inv, e2*inv, e3*inv };
            if (idx < 512) {
                const int e = idx >> 6, kk = idx & 63;
#pragma unroll
                for (int hd = 0; hd < 4; hd++)
                    v += wi[hd] * he_w2[(e*256 + hd*64 + col)*64 + kk];
            } else if (idx < 1024) {
                const int e = (idx - 512) >> 6, kk = idx & 63;
#pragma unroll
                for (int hd = 0; hd < 4; hd++)
                    v += wi[hd] * ha_w2[(e*256 + hd*64 + col)*64 + kk];
            } else if (idx < 1032) {
                const int e = idx - 1024;
#pragma unroll
                for (int hd = 0; hd < 4; hd++)
                    v += wi[hd] * he_b2[e*256 + hd*64 + col];
            } else {
                const int e = idx - 1032;
#pragma unroll
                for (int hd = 0; hd < 4; hd++)
                    v += wi[hd] * ha_b2[e*256 + hd*64 + col];
            }
        }
        ((unsigned short*)ws)[tid] = to_bf16(v);
    } else if (tid < 100352) {
        // GRU Wpack[T][kstep][fl][j]: k interleaved x|h (even k -> ih row k/2, odd -> hh)
        const int t = tid - 67584;
        const int j  = t & 7;
        const int fl = (t >> 3) & 63;
        const int kstep = (t >> 9) & 3;
        const int T  = t >> 11;                 // 0..15
        const int k  = kstep*32 + ((fl >> 4) << 3) + j;   // 0..127
        const int kk = k >> 1;                  // 0..63
        const bool hside = (k & 1);
        const int c  = T*16 + (fl & 15);        // 0..255
        const int g  = c >> 6;
        const int u  = c & 63;
        float v;
        if (g == 0)      v = hside ? gru_w_hh[u*64 + kk]       : gru_w_ih[u*64 + kk];
        else if (g == 1) v = hside ? gru_w_hh[(64+u)*64 + kk]  : gru_w_ih[(64+u)*64 + kk];
        else if (g == 2) v = hside ? 0.f                        : gru_w_ih[(128+u)*64 + kk];
        else             v = hside ? gru_w_hh[(128+u)*64 + kk] : 0.f;
        ((unsigned short*)ws)[WGRU_US + t] = to_bf16(v);
    } else if (tid < 104448) {
        const int t = tid - 100352;
        const int k = t >> 6, hp = t & 63;
        float v = wo0 * he_w2[(2048 + 0*64 + hp)*64 + k]
                + wo1 * he_w2[(2048 + 1*64 + hp)*64 + k]
                + wo2 * he_w2[(2048 + 2*64 + hp)*64 + k]
                + wo3 * he_w2[(2048 + 3*64 + hp)*64 + k];
        ws[WCT2_OFF + t] = v;
    } else if (tid < 104512) {
        const int k = tid - 104448;
        float v = wo0*he_w2[(2304+0)*64 + k] + wo1*he_w2[(2304+1)*64 + k]
                + wo2*he_w2[(2304+2)*64 + k] + wo3*he_w2[(2304+3)*64 + k];
        ws[WB_OFF + k] = v;
    } else if (tid < 104576) {
        const int hp = tid - 104512;
        float v = wo0*he_b2[2048 + 0*64 + hp] + wo1*he_b2[2048 + 1*64 + hp]
                + wo2*he_b2[2048 + 2*64 + hp] + wo3*he_b2[2048 + 3*64 + hp];
        ws[BB_OFF + hp] = v;
    } else if (tid == 104576) {
        ws[CC_OFF] = wo0*he_b2[2304] + wo1*he_b2[2305] + wo2*he_b2[2306] + wo3*he_b2[2307];
    } else if (tid < 104640) {
        // pad
    } else if (tid < 104896) {
        const int c = tid - 104640;
        const int g = c >> 6, u = c & 63;
        float v;
        if (g == 0)      v = gru_b_ih[u]       + gru_b_hh[u];
        else if (g == 1) v = gru_b_ih[64 + u]  + gru_b_hh[64 + u];
        else if (g == 2) v = gru_b_ih[128 + u];
        else             v = gru_b_hh[128 + u];
        ws[B4_OFF + c] = v;
    } else if (tid < 105792) {
        const int t = tid - 104896; const int j = t >> 6, hp = t & 63;
        ws[FC1T_OFF + t] = fc1_own_w[hp*OWN_ + j];
    }
}

__device__ __forceinline__ float wave_red(float v) {
#pragma unroll
    for (int off = 32; off; off >>= 1) v += __shfl_xor(v, off);
    return v;
}

__global__ __launch_bounds__(256) void main_kernel(
    const float* __restrict__ own_feats,
    const float* __restrict__ enemy_feats,
    const float* __restrict__ ally_feats,
    const float* __restrict__ hidden_state,
    const int*   __restrict__ agent_idx,
    const int*   __restrict__ last_act,
    const float* __restrict__ fc1_own_b,
    const float* __restrict__ agent_emb,
    const float* __restrict__ action_emb,
    const float* __restrict__ he_w1,
    const float* __restrict__ he_b1,
    const float* __restrict__ ha_w1,
    const float* __restrict__ ha_b1,
    const float* __restrict__ fc2_w,
    const float* __restrict__ fc2_b,
    const float* __restrict__ ws,
    float* __restrict__ out)
{
    const int tid  = threadIdx.x;
    const int w    = tid >> 6;        // wave id 0..3 == agent slot
    const int lane = tid & 63;
    const int n    = blockIdx.x * 4 + w;

    // Compact A-buffer: only real agent rows (0..3). k is block-permuted to make
    // phase-1 writes contiguous per lane. Later reused (aliased) as GRU x|h buffer.
    __shared__ __align__(16) unsigned short a_cmp[4][1056];   // 8448 B
    __shared__ float Gm[4][260];                               // 4160 B
    __shared__ float pembM[4][64];
    __shared__ float hh_lds[4][68];

    // ================= Phase 1: per-agent activations (wave = agent) ========
    float h_e[NE_];
    float embo, hin_reg;
    {
        const float4 w1a  = *(const float4*)(he_w1 + lane*8);
        const float4 w1b  = *(const float4*)(he_w1 + lane*8 + 4);
        const float  hb1  = he_b1[lane];

        float ps[8] = {0,0,0,0,0,0,0,0};
#pragma unroll
        for (int ei = 0; ei < NE_; ei++) {
            const float* ef = enemy_feats + (size_t)(n*NE_ + ei)*EDIM_;
            const float4 e0 = *(const float4*)ef;
            const float4 e1 = *(const float4*)(ef + 4);
            float h = hb1;
            h = fmaf(e0.x, w1a.x, h); h = fmaf(e0.y, w1a.y, h);
            h = fmaf(e0.z, w1a.z, h); h = fmaf(e0.w, w1a.w, h);
            h = fmaf(e1.x, w1b.x, h); h = fmaf(e1.y, w1b.y, h);
            h = fmaf(e1.z, w1b.z, h); h = fmaf(e1.w, w1b.w, h);
            h = fmaxf(h, 0.f);
            h_e[ei] = h;
            ps[0] = fmaf(e0.x, h, ps[0]); ps[1] = fmaf(e0.y, h, ps[1]);
            ps[2] = fmaf(e0.z, h, ps[2]); ps[3] = fmaf(e0.w, h, ps[3]);
            ps[4] = fmaf(e1.x, h, ps[4]); ps[5] = fmaf(e1.y, h, ps[5]);
            ps[6] = fmaf(e1.z, h, ps[6]); ps[7] = fmaf(e1.w, h, ps[7]);
        }
        // write k = lane*8 + e  (one b128 store)
        {
            uint4 pk;
            pk.x = pack2(ps[0], ps[1]); pk.y = pack2(ps[2], ps[3]);
            pk.z = pack2(ps[4], ps[5]); pk.w = pack2(ps[6], ps[7]);
            *(uint4*)&a_cmp[w][lane*8] = pk;
        }

        const float4 wa1a = *(const float4*)(ha_w1 + lane*8);
        const float4 wa1b = *(const float4*)(ha_w1 + lane*8 + 4);
        const float  hba1 = ha_b1[lane];
        float pa[8] = {0,0,0,0,0,0,0,0};
#pragma unroll
        for (int ai = 0; ai < NAL_; ai++) {
            const float* af = ally_feats + (size_t)(n*NAL_ + ai)*ADIM_;
            const float4 a0 = *(const float4*)af;
            const float4 a1 = *(const float4*)(af + 4);
            float h = hba1;
            h = fmaf(a0.x, wa1a.x, h); h = fmaf(a0.y, wa1a.y, h);
            h = fmaf(a0.z, wa1a.z, h); h = fmaf(a0.w, wa1a.w, h);
            h = fmaf(a1.x, wa1b.x, h); h = fmaf(a1.y, wa1b.y, h);
            h = fmaf(a1.z, wa1b.z, h); h = fmaf(a1.w, wa1b.w, h);
            h = fmaxf(h, 0.f);
            pa[0] = fmaf(a0.x, h, pa[0]); pa[1] = fmaf(a0.y, h, pa[1]);
            pa[2] = fmaf(a0.z, h, pa[2]); pa[3] = fmaf(a0.w, h, pa[3]);
            pa[4] = fmaf(a1.x, h, pa[4]); pa[5] = fmaf(a1.y, h, pa[5]);
            pa[6] = fmaf(a1.z, h, pa[6]); pa[7] = fmaf(a1.w, h, pa[7]);
        }
        {
            uint4 pk;
            pk.x = pack2(pa[0], pa[1]); pk.y = pack2(pa[2], pa[3]);
            pk.z = pack2(pa[4], pa[5]); pk.w = pack2(pa[6], pa[7]);
            *(uint4*)&a_cmp[w][512 + lane*8] = pk;
        }

        // feature sums at k = 1024..1039 (identity-mapped); zero tail 1040..1055
        if (lane < 8) {
            float s = 0.f;
            for (int ei = 0; ei < NE_; ei++) s += enemy_feats[(size_t)(n*NE_ + ei)*EDIM_ + lane];
            a_cmp[w][1024 + lane] = to_bf16(s);
        } else if (lane < 16) {
            const int p = lane - 8;
            float s = 0.f;
            for (int ai = 0; ai < NAL_; ai++) s += ally_feats[(size_t)(n*NAL_ + ai)*ADIM_ + p];
            a_cmp[w][1032 + p] = to_bf16(s);
        } else if (lane < 32) {
            a_cmp[w][1024 + lane] = 0;   // k 1040..1055
        }

        float e = fc1_own_b[lane];
        const float* ow = own_feats + (size_t)n*OWN_;
#pragma unroll
        for (int j = 0; j < OWN_; j++) e = fmaf(ow[j], ws[FC1T_OFF + j*64 + lane], e);
        e += agent_emb[agent_idx[n]*64 + lane];
        e += action_emb[last_act[n]*64 + lane];
        embo = e;

        hin_reg = hidden_state[(size_t)n*64 + lane];
    }
    __syncthreads();

    // ================= Phase 2: MFMA  emb[4x64] = A[4x1056] * W[1056x64] ====
    // A rows 4..15 are clamped duplicates (lane&3) -> D rows 4..15 unread.
    {
        f32x4 acc0 = {0.f, 0.f, 0.f, 0.f};
        f32x4 acc1 = {0.f, 0.f, 0.f, 0.f};
        const unsigned short* wpw = (const unsigned short*)ws + ((w * 33) << 9);
        const unsigned short* arow = &a_cmp[lane & 3][(lane >> 4) << 3];
#pragma unroll 8
        for (int ks = 0; ks < 32; ks += 2) {
            const short8_t a0 = *(const short8_t*)&arow[ks << 5];
            const short8_t b0 = *(const short8_t*)&wpw[(ks << 9) + (lane << 3)];
            acc0 = __builtin_amdgcn_mfma_f32_16x16x32_bf16(a0, b0, acc0, 0, 0, 0);
            const short8_t a1 = *(const short8_t*)&arow[(ks+1) << 5];
            const short8_t b1 = *(const short8_t*)&wpw[((ks+1) << 9) + (lane << 3)];
            acc1 = __builtin_amdgcn_mfma_f32_16x16x32_bf16(a1, b1, acc1, 0, 0, 0);
        }
        {
            const short8_t a0 = *(const short8_t*)&arow[32 << 5];
            const short8_t b0 = *(const short8_t*)&wpw[(32 << 9) + (lane << 3)];
            acc0 = __builtin_amdgcn_mfma_f32_16x16x32_bf16(a0, b0, acc0, 0, 0, 0);
        }
        if (lane < 16) {
#pragma unroll
            for (int r = 0; r < 4; ++r) pembM[r][(w << 4) + lane] = acc0[r] + acc1[r];
        }
    }
    __syncthreads();

    // ============ GRU stage A: x|h interleaved bf16 into a_cmp[0..511] ======
    {
        const float x = fmaxf(embo + pembM[w][lane], 0.f);
        // k = 2*lane (x), 2*lane+1 (h): one b32 store
        *(unsigned*)&((unsigned short*)a_cmp)[w*128 + lane*2] = pack2(x, hin_reg);
    }
    __syncthreads();

    // ============ GRU stage B: MFMA G[4x256] = [x|h][4x128] * Wgru ==========
    {
        const unsigned short* xc = (const unsigned short*)a_cmp;
        short8_t afr[4];
#pragma unroll
        for (int kstep = 0; kstep < 4; ++kstep)
            afr[kstep] = *(const short8_t*)&xc[(lane & 3)*128 + ((lane >> 4) << 3) + (kstep << 5)];

        const unsigned short* wg = (const unsigned short*)ws + WGRU_US;
#pragma unroll
        for (int tt = 0; tt < 4; ++tt) {
            const int T = (w << 2) + tt;
            const float b = ws[B4_OFF + (T << 4) + (lane & 15)];
            f32x4 acc = {b, b, b, b};
#pragma unroll
            for (int kstep = 0; kstep < 4; ++kstep) {
                const short8_t bfr = *(const short8_t*)&wg[(((T << 2) + kstep) << 9) + (lane << 3)];
                acc = __builtin_amdgcn_mfma_f32_16x16x32_bf16(afr[kstep], bfr, acc, 0, 0, 0);
            }
            if (lane < 16) {
#pragma unroll
                for (int r = 0; r < 4; ++r) Gm[r][(T << 4) + lane] = acc[r];
            }
        }
    }
    __syncthreads();

    // ============ GRU stage C (wave-private) + epilogue =====================
    float hh;
    {
        const float gr = Gm[w][lane];
        const float gz = Gm[w][64 + lane];
        const float gi = Gm[w][128 + lane];
        const float gh = Gm[w][192 + lane];
        const float r = 1.f / (1.f + expf(-gr));
        const float z = 1.f / (1.f + expf(-gz));
        const float t = tanhf(gi + r * gh);
        hh = (1.f - z) * t + z * hin_reg;
        hh_lds[w][lane] = hh;       // same-wave RAW below (lgkmcnt, no barrier)
    }

    {
        float prods[18];
#pragma unroll
        for (int l = 0; l < 6; l++) prods[l] = hh * fc2_w[l*64 + lane];
        prods[6] = hh * ws[BB_OFF + lane];

        float vv = ws[WB_OFF + lane];
        const float* wct = ws + WCT2_OFF + lane*64;
#pragma unroll
        for (int j4 = 0; j4 < 64; j4 += 4) {
            const float4 hh4 = *(const float4*)&hh_lds[w][j4];
            const float4 wv  = *(const float4*)(wct + j4);
            vv = fmaf(hh4.x, wv.x, vv);
            vv = fmaf(hh4.y, wv.y, vv);
            vv = fmaf(hh4.z, wv.z, vv);
            vv = fmaf(hh4.w, wv.w, vv);
        }

#pragma unroll
        for (int ei = 0; ei < NE_; ei++) prods[7 + ei] = vv * h_e[ei];

#pragma unroll
        for (int i = 0; i < 18; i++) prods[i] = wave_red(prods[i]);

        if (lane == 0) {
            float* o = out + (size_t)n*17;
            const float sn = prods[6] + ws[CC_OFF];
#pragma unroll
            for (int l = 0; l < 6; l++) o[l] = prods[l] + fc2_b[l];
#pragma unroll
            for (int ei = 0; ei < NE_; ei++) o[6 + ei] = prods[7 + ei] + sn;
        }
    }
}

extern "C" void kernel_launch(void* const* d_in, const int* in_sizes, int n_in,
                              void* d_out, int out_size, void* d_ws, size_t ws_size,
                              hipStream_t stream)
{
    const float* own_feats   = (const float*)d_in[0];
    const float* enemy_feats = (const float*)d_in[1];
    const float* ally_feats  = (const float*)d_in[2];
    const float* hidden      = (const float*)d_in[3];
    const int*   agent_idx   = (const int*)d_in[4];
    const int*   last_act    = (const int*)d_in[5];
    const float* fc1_own_w   = (const float*)d_in[6];
    const float* fc1_own_b   = (const float*)d_in[7];
    const float* agent_emb   = (const float*)d_in[8];
    const float* action_emb  = (const float*)d_in[9];
    const float* he_w1       = (const float*)d_in[10];
    const float* he_b1       = (const float*)d_in[11];
    const float* he_w2       = (const float*)d_in[12];
    const float* he_b2       = (const float*)d_in[13];
    const float* ha_w1       = (const float*)d_in[14];
    const float* ha_b1       = (const float*)d_in[15];
    const float* ha_w2       = (const float*)d_in[16];
    const float* ha_b2       = (const float*)d_in[17];
    const float* merge_in_w  = (const float*)d_in[18];
    const float* gru_w_ih    = (const float*)d_in[19];
    const float* gru_w_hh    = (const float*)d_in[20];
    const float* gru_b_ih    = (const float*)d_in[21];
    const float* gru_b_hh    = (const float*)d_in[22];
    const float* fc2_w       = (const float*)d_in[23];
    const float* fc2_b       = (const float*)d_in[24];
    const float* merge_out_w = (const float*)d_in[25];
    float* out = (float*)d_out;
    float* ws  = (float*)d_ws;

    hipLaunchKernelGGL(prep_kernel, dim3(414), dim3(256), 0, stream,
                       fc1_own_w, he_w2, he_b2, ha_w2, ha_b2, merge_in_w,
                       gru_w_ih, gru_w_hh, gru_b_ih, gru_b_hh, merge_out_w, ws);
    hipLaunchKernelGGL(main_kernel, dim3(NTOT_/4), dim3(256), 0, stream,
                       own_feats, enemy_feats, ally_feats, hidden, agent_idx, last_act,
                       fc1_own_b, agent_emb, action_emb, he_w1, he_b1, ha_w1, ha_b1,
                       fc2_w, fc2_b, ws, out);
}

// Round 8
// 41.291 us; speedup vs baseline: 1.9713x; 1.1425x over previous
//
#include <hip/hip_runtime.h>
#include <hip/hip_bf16.h>
#include <math.h>

// Problem constants
#define BS_    512
#define NA_    10
#define NE_    11
#define NAL_   9
#define H_     64
#define HEADS_ 4
#define EDIM_  8
#define ADIM_  8
#define OWN_   14
#define HYP_   64
#define NTOT_  (BS_*NA_)   // 5120
#define AGB_   8           // agents per block

// ws layout:
//   ushort [0, 67584):        phase2 Wpack[q][ks][fl][j] bf16 (4 x 33 x 64 x 8), K-permuted
//   ushort [67584, 100352):   GRU Wpack[T][kstep][fl][j] bf16 (16 x 4 x 64 x 8), x|h interleaved
//   float offsets (1 float = 2 ushorts):
#define WGRU_US   67584
#define WCT2_OFF  50176     // [64][64]  WCT2[k][h']
#define WB_OFF    54272     // [64]
#define BB_OFF    54336     // [64]
#define CC_OFF    54400     // [1]
#define B4_OFF    54464     // [256] gru bias (r | z | i_n | h_n)
#define FC1T_OFF  54720     // [14][64]
#define WS_FLOATS 55616

typedef __attribute__((ext_vector_type(8))) short short8_t;
typedef __attribute__((ext_vector_type(4))) float f32x4;

__device__ __forceinline__ unsigned short to_bf16(float v) {
    unsigned u = __float_as_uint(v);
    u += 0x7fffu + ((u >> 16) & 1u);
    return (unsigned short)(u >> 16);
}
__device__ __forceinline__ unsigned pack2(float lo, float hi) {
    return ((unsigned)to_bf16(hi) << 16) | to_bf16(lo);
}

__global__ __launch_bounds__(256) void prep_kernel(
    const float* __restrict__ fc1_own_w,
    const float* __restrict__ he_w2, const float* __restrict__ he_b2,
    const float* __restrict__ ha_w2, const float* __restrict__ ha_b2,
    const float* __restrict__ merge_in_w,
    const float* __restrict__ gru_w_ih, const float* __restrict__ gru_w_hh,
    const float* __restrict__ gru_b_ih, const float* __restrict__ gru_b_hh,
    const float* __restrict__ merge_out_w,
    float* __restrict__ ws)
{
    const int tid = blockIdx.x * blockDim.x + threadIdx.x;

    float wo0, wo1, wo2, wo3;
    {
        float e0 = expf(merge_out_w[0]), e1 = expf(merge_out_w[1]);
        float e2 = expf(merge_out_w[2]), e3 = expf(merge_out_w[3]);
        float inv = 1.0f / (e0 + e1 + e2 + e3);
        wo0 = e0*inv; wo1 = e1*inv; wo2 = e2*inv; wo3 = e3*inv;
    }

    if (tid < 67584) {
        // phase-2 Wpack: fragment position (q,ks,l,j) -> k -> permuted source row idx
        int t = tid;
        const int j  = t & 7;  t >>= 3;
        const int l  = t & 63; t >>= 6;
        const int ks = t % 33;
        const int q  = t / 33;
        const int k  = ks*32 + ((l >> 4) << 3) + j;
        const int col = (q << 4) + (l & 15);
        int idx;
        if (k < 512)       idx = ((k & 7) << 6) + (k >> 3);
        else if (k < 1024) idx = 512 + ((((k-512) & 7) << 6) + ((k-512) >> 3));
        else               idx = k;
        float v = 0.f;
        if (idx < 1040) {
            const float e0 = expf(merge_in_w[0*64 + col]), e1 = expf(merge_in_w[1*64 + col]);
            const float e2 = expf(merge_in_w[2*64 + col]), e3 = expf(merge_in_w[3*64 + col]);
            const float inv = 1.0f / (e0 + e1 + e2 + e3);
            const float wi[4] = { e0*inv, e1*inv, e2*inv, e3*inv };
            if (idx < 512) {
                const int e = idx >> 6, kk = idx & 63;
#pragma unroll
                for (int hd = 0; hd < 4; hd++)
                    v += wi[hd] * he_w2[(e*256 + hd*64 + col)*64 + kk];
            } else if (idx < 1024) {
                const int e = (idx - 512) >> 6, kk = idx & 63;
#pragma unroll
                for (int hd = 0; hd < 4; hd++)
                    v += wi[hd] * ha_w2[(e*256 + hd*64 + col)*64 + kk];
            } else if (idx < 1032) {
                const int e = idx - 1024;
#pragma unroll
                for (int hd = 0; hd < 4; hd++)
                    v += wi[hd] * he_b2[e*256 + hd*64 + col];
            } else {
                const int e = idx - 1032;
#pragma unroll
                for (int hd = 0; hd < 4; hd++)
                    v += wi[hd] * ha_b2[e*256 + hd*64 + col];
            }
        }
        ((unsigned short*)ws)[tid] = to_bf16(v);
    } else if (tid < 100352) {
        // GRU Wpack[T][kstep][fl][j]: k interleaved x|h
        const int t = tid - 67584;
        const int j  = t & 7;
        const int fl = (t >> 3) & 63;
        const int kstep = (t >> 9) & 3;
        const int T  = t >> 11;
        const int k  = kstep*32 + ((fl >> 4) << 3) + j;
        const int kk = k >> 1;
        const bool hside = (k & 1);
        const int c  = T*16 + (fl & 15);
        const int g  = c >> 6;
        const int u  = c & 63;
        float v;
        if (g == 0)      v = hside ? gru_w_hh[u*64 + kk]       : gru_w_ih[u*64 + kk];
        else if (g == 1) v = hside ? gru_w_hh[(64+u)*64 + kk]  : gru_w_ih[(64+u)*64 + kk];
        else if (g == 2) v = hside ? 0.f                        : gru_w_ih[(128+u)*64 + kk];
        else             v = hside ? gru_w_hh[(128+u)*64 + kk] : 0.f;
        ((unsigned short*)ws)[WGRU_US + t] = to_bf16(v);
    } else if (tid < 104448) {
        const int t = tid - 100352;
        const int k = t >> 6, hp = t & 63;
        float v = wo0 * he_w2[(2048 + 0*64 + hp)*64 + k]
                + wo1 * he_w2[(2048 + 1*64 + hp)*64 + k]
                + wo2 * he_w2[(2048 + 2*64 + hp)*64 + k]
                + wo3 * he_w2[(2048 + 3*64 + hp)*64 + k];
        ws[WCT2_OFF + t] = v;
    } else if (tid < 104512) {
        const int k = tid - 104448;
        float v = wo0*he_w2[(2304+0)*64 + k] + wo1*he_w2[(2304+1)*64 + k]
                + wo2*he_w2[(2304+2)*64 + k] + wo3*he_w2[(2304+3)*64 + k];
        ws[WB_OFF + k] = v;
    } else if (tid < 104576) {
        const int hp = tid - 104512;
        float v = wo0*he_b2[2048 + 0*64 + hp] + wo1*he_b2[2048 + 1*64 + hp]
                + wo2*he_b2[2048 + 2*64 + hp] + wo3*he_b2[2048 + 3*64 + hp];
        ws[BB_OFF + hp] = v;
    } else if (tid == 104576) {
        ws[CC_OFF] = wo0*he_b2[2304] + wo1*he_b2[2305] + wo2*he_b2[2306] + wo3*he_b2[2307];
    } else if (tid < 104640) {
        // pad
    } else if (tid < 104896) {
        const int c = tid - 104640;
        const int g = c >> 6, u = c & 63;
        float v;
        if (g == 0)      v = gru_b_ih[u]       + gru_b_hh[u];
        else if (g == 1) v = gru_b_ih[64 + u]  + gru_b_hh[64 + u];
        else if (g == 2) v = gru_b_ih[128 + u];
        else             v = gru_b_hh[128 + u];
        ws[B4_OFF + c] = v;
    } else if (tid < 105792) {
        const int t = tid - 104896; const int j = t >> 6, hp = t & 63;
        ws[FC1T_OFF + t] = fc1_own_w[hp*OWN_ + j];
    }
}

__device__ __forceinline__ float wave_red(float v) {
#pragma unroll
    for (int off = 32; off; off >>= 1) v += __shfl_xor(v, off);
    return v;
}

__global__ __launch_bounds__(512) void main_kernel(
    const float* __restrict__ own_feats,
    const float* __restrict__ enemy_feats,
    const float* __restrict__ ally_feats,
    const float* __restrict__ hidden_state,
    const int*   __restrict__ agent_idx,
    const int*   __restrict__ last_act,
    const float* __restrict__ fc1_own_b,
    const float* __restrict__ agent_emb,
    const float* __restrict__ action_emb,
    const float* __restrict__ he_w1,
    const float* __restrict__ he_b1,
    const float* __restrict__ ha_w1,
    const float* __restrict__ ha_b1,
    const float* __restrict__ fc2_w,
    const float* __restrict__ fc2_b,
    const float* __restrict__ ws,
    float* __restrict__ out)
{
    const int tid  = threadIdx.x;
    const int w    = tid >> 6;        // wave id 0..7 == agent slot
    const int lane = tid & 63;
    const int n    = blockIdx.x * AGB_ + w;

    __shared__ __align__(16) unsigned short a_cmp[AGB_][1056];  // 16896 B
    __shared__ float Gm[AGB_][260];                             // 8320 B
    __shared__ float pembM[2][AGB_][64];                        // 4096 B
    __shared__ float hh_lds[AGB_][68];                          // 2176 B

    // ================= Phase 1: per-agent activations (wave = agent) ========
    float h_e[NE_];
    float embo, hin_reg;
    {
        const float4 w1a  = *(const float4*)(he_w1 + lane*8);
        const float4 w1b  = *(const float4*)(he_w1 + lane*8 + 4);
        const float  hb1  = he_b1[lane];

        float ps[8] = {0,0,0,0,0,0,0,0};
#pragma unroll
        for (int ei = 0; ei < NE_; ei++) {
            const float* ef = enemy_feats + (size_t)(n*NE_ + ei)*EDIM_;
            const float4 e0 = *(const float4*)ef;
            const float4 e1 = *(const float4*)(ef + 4);
            float h = hb1;
            h = fmaf(e0.x, w1a.x, h); h = fmaf(e0.y, w1a.y, h);
            h = fmaf(e0.z, w1a.z, h); h = fmaf(e0.w, w1a.w, h);
            h = fmaf(e1.x, w1b.x, h); h = fmaf(e1.y, w1b.y, h);
            h = fmaf(e1.z, w1b.z, h); h = fmaf(e1.w, w1b.w, h);
            h = fmaxf(h, 0.f);
            h_e[ei] = h;
            ps[0] = fmaf(e0.x, h, ps[0]); ps[1] = fmaf(e0.y, h, ps[1]);
            ps[2] = fmaf(e0.z, h, ps[2]); ps[3] = fmaf(e0.w, h, ps[3]);
            ps[4] = fmaf(e1.x, h, ps[4]); ps[5] = fmaf(e1.y, h, ps[5]);
            ps[6] = fmaf(e1.z, h, ps[6]); ps[7] = fmaf(e1.w, h, ps[7]);
        }
        {
            uint4 pk;
            pk.x = pack2(ps[0], ps[1]); pk.y = pack2(ps[2], ps[3]);
            pk.z = pack2(ps[4], ps[5]); pk.w = pack2(ps[6], ps[7]);
            *(uint4*)&a_cmp[w][lane*8] = pk;
        }

        const float4 wa1a = *(const float4*)(ha_w1 + lane*8);
        const float4 wa1b = *(const float4*)(ha_w1 + lane*8 + 4);
        const float  hba1 = ha_b1[lane];
        float pa[8] = {0,0,0,0,0,0,0,0};
#pragma unroll
        for (int ai = 0; ai < NAL_; ai++) {
            const float* af = ally_feats + (size_t)(n*NAL_ + ai)*ADIM_;
            const float4 a0 = *(const float4*)af;
            const float4 a1 = *(const float4*)(af + 4);
            float h = hba1;
            h = fmaf(a0.x, wa1a.x, h); h = fmaf(a0.y, wa1a.y, h);
            h = fmaf(a0.z, wa1a.z, h); h = fmaf(a0.w, wa1a.w, h);
            h = fmaf(a1.x, wa1b.x, h); h = fmaf(a1.y, wa1b.y, h);
            h = fmaf(a1.z, wa1b.z, h); h = fmaf(a1.w, wa1b.w, h);
            h = fmaxf(h, 0.f);
            pa[0] = fmaf(a0.x, h, pa[0]); pa[1] = fmaf(a0.y, h, pa[1]);
            pa[2] = fmaf(a0.z, h, pa[2]); pa[3] = fmaf(a0.w, h, pa[3]);
            pa[4] = fmaf(a1.x, h, pa[4]); pa[5] = fmaf(a1.y, h, pa[5]);
            pa[6] = fmaf(a1.z, h, pa[6]); pa[7] = fmaf(a1.w, h, pa[7]);
        }
        {
            uint4 pk;
            pk.x = pack2(pa[0], pa[1]); pk.y = pack2(pa[2], pa[3]);
            pk.z = pack2(pa[4], pa[5]); pk.w = pack2(pa[6], pa[7]);
            *(uint4*)&a_cmp[w][512 + lane*8] = pk;
        }

        if (lane < 8) {
            float s = 0.f;
            for (int ei = 0; ei < NE_; ei++) s += enemy_feats[(size_t)(n*NE_ + ei)*EDIM_ + lane];
            a_cmp[w][1024 + lane] = to_bf16(s);
        } else if (lane < 16) {
            const int p = lane - 8;
            float s = 0.f;
            for (int ai = 0; ai < NAL_; ai++) s += ally_feats[(size_t)(n*NAL_ + ai)*ADIM_ + p];
            a_cmp[w][1032 + p] = to_bf16(s);
        } else if (lane < 32) {
            a_cmp[w][1024 + lane] = 0;   // k 1040..1055
        }

        float e = fc1_own_b[lane];
        const float* ow = own_feats + (size_t)n*OWN_;
#pragma unroll
        for (int j = 0; j < OWN_; j++) e = fmaf(ow[j], ws[FC1T_OFF + j*64 + lane], e);
        e += agent_emb[agent_idx[n]*64 + lane];
        e += action_emb[last_act[n]*64 + lane];
        embo = e;

        hin_reg = hidden_state[(size_t)n*64 + lane];
    }
    __syncthreads();

    // ====== Phase 2: MFMA emb[8x64] = A[8x1056]*W[1056x64], wave=(quad,Khalf)
    // A rows 8..15 are clamped duplicates (lane&7) -> D rows 8..15 unread.
    {
        const int q  = w & 3;
        const int kh = w >> 2;
        const int ksa = kh ? 17 : 0;
        const int ksb = kh ? 33 : 17;
        f32x4 acc0 = {0.f, 0.f, 0.f, 0.f};
        f32x4 acc1 = {0.f, 0.f, 0.f, 0.f};
        const unsigned short* wpw = (const unsigned short*)ws + ((q * 33) << 9);
        const unsigned short* arow = &a_cmp[lane & 7][(lane >> 4) << 3];
        for (int ks = ksa; ks + 1 < ksb; ks += 2) {
            const short8_t a0 = *(const short8_t*)&arow[ks << 5];
            const short8_t b0 = *(const short8_t*)&wpw[(ks << 9) + (lane << 3)];
            acc0 = __builtin_amdgcn_mfma_f32_16x16x32_bf16(a0, b0, acc0, 0, 0, 0);
            const short8_t a1 = *(const short8_t*)&arow[(ks+1) << 5];
            const short8_t b1 = *(const short8_t*)&wpw[((ks+1) << 9) + (lane << 3)];
            acc1 = __builtin_amdgcn_mfma_f32_16x16x32_bf16(a1, b1, acc1, 0, 0, 0);
        }
        if (((ksb - ksa) & 1)) {
            const int ks = ksb - 1;
            const short8_t a0 = *(const short8_t*)&arow[ks << 5];
            const short8_t b0 = *(const short8_t*)&wpw[(ks << 9) + (lane << 3)];
            acc0 = __builtin_amdgcn_mfma_f32_16x16x32_bf16(a0, b0, acc0, 0, 0, 0);
        }
        if (lane < 32) {
            const int row = (lane >> 4) * 4;   // + r
#pragma unroll
            for (int r = 0; r < 4; ++r)
                pembM[kh][row + r][(q << 4) + (lane & 15)] = acc0[r] + acc1[r];
        }
    }
    __syncthreads();

    // ============ GRU stage A: x|h interleaved bf16 into a_cmp rows =========
    {
        const float x = fmaxf(embo + pembM[0][w][lane] + pembM[1][w][lane], 0.f);
        *(unsigned*)&a_cmp[w][lane*2] = pack2(x, hin_reg);
    }
    __syncthreads();

    // ============ GRU stage B: MFMA G[8x256] = [x|h][8x128]*Wgru, 2 T/wave ==
    {
        short8_t afr[4];
#pragma unroll
        for (int kstep = 0; kstep < 4; ++kstep)
            afr[kstep] = *(const short8_t*)&a_cmp[lane & 7][((lane >> 4) << 3) + (kstep << 5)];

        const unsigned short* wg = (const unsigned short*)ws + WGRU_US;
#pragma unroll
        for (int tt = 0; tt < 2; ++tt) {
            const int T = (w << 1) + tt;
            const float b = ws[B4_OFF + (T << 4) + (lane & 15)];
            f32x4 acc = {b, b, b, b};
#pragma unroll
            for (int kstep = 0; kstep < 4; ++kstep) {
                const short8_t bfr = *(const short8_t*)&wg[(((T << 2) + kstep) << 9) + (lane << 3)];
                acc = __builtin_amdgcn_mfma_f32_16x16x32_bf16(afr[kstep], bfr, acc, 0, 0, 0);
            }
            if (lane < 32) {
                const int row = (lane >> 4) * 4;
#pragma unroll
                for (int r = 0; r < 4; ++r) Gm[row + r][(T << 4) + (lane & 15)] = acc[r];
            }
        }
    }
    __syncthreads();

    // ============ GRU stage C (wave-private) + epilogue =====================
    float hh;
    {
        const float gr = Gm[w][lane];
        const float gz = Gm[w][64 + lane];
        const float gi = Gm[w][128 + lane];
        const float gh = Gm[w][192 + lane];
        const float r = 1.f / (1.f + expf(-gr));
        const float z = 1.f / (1.f + expf(-gz));
        const float t = tanhf(gi + r * gh);
        hh = (1.f - z) * t + z * hin_reg;
        hh_lds[w][lane] = hh;       // same-wave RAW below
    }

    {
        float prods[18];
#pragma unroll
        for (int l = 0; l < 6; l++) prods[l] = hh * fc2_w[l*64 + lane];
        prods[6] = hh * ws[BB_OFF + lane];

        float vv = ws[WB_OFF + lane];
        const float* wct = ws + WCT2_OFF + lane*64;
#pragma unroll
        for (int j4 = 0; j4 < 64; j4 += 4) {
            const float4 hh4 = *(const float4*)&hh_lds[w][j4];
            const float4 wv  = *(const float4*)(wct + j4);
            vv = fmaf(hh4.x, wv.x, vv);
            vv = fmaf(hh4.y, wv.y, vv);
            vv = fmaf(hh4.z, wv.z, vv);
            vv = fmaf(hh4.w, wv.w, vv);
        }

#pragma unroll
        for (int ei = 0; ei < NE_; ei++) prods[7 + ei] = vv * h_e[ei];

#pragma unroll
        for (int i = 0; i < 18; i++) prods[i] = wave_red(prods[i]);

        if (lane == 0) {
            float* o = out + (size_t)n*17;
            const float sn = prods[6] + ws[CC_OFF];
#pragma unroll
            for (int l = 0; l < 6; l++) o[l] = prods[l] + fc2_b[l];
#pragma unroll
            for (int ei = 0; ei < NE_; ei++) o[6 + ei] = prods[7 + ei] + sn;
        }
    }
}

extern "C" void kernel_launch(void* const* d_in, const int* in_sizes, int n_in,
                              void* d_out, int out_size, void* d_ws, size_t ws_size,
                              hipStream_t stream)
{
    const float* own_feats   = (const float*)d_in[0];
    const float* enemy_feats = (const float*)d_in[1];
    const float* ally_feats  = (const float*)d_in[2];
    const float* hidden      = (const float*)d_in[3];
    const int*   agent_idx   = (const int*)d_in[4];
    const int*   last_act    = (const int*)d_in[5];
    const float* fc1_own_w   = (const float*)d_in[6];
    const float* fc1_own_b   = (const float*)d_in[7];
    const float* agent_emb   = (const float*)d_in[8];
    const float* action_emb  = (const float*)d_in[9];
    const float* he_w1       = (const float*)d_in[10];
    const float* he_b1       = (const float*)d_in[11];
    const float* he_w2       = (const float*)d_in[12];
    const float* he_b2       = (const float*)d_in[13];
    const float* ha_w1       = (const float*)d_in[14];
    const float* ha_b1       = (const float*)d_in[15];
    const float* ha_w2       = (const float*)d_in[16];
    const float* ha_b2       = (const float*)d_in[17];
    const float* merge_in_w  = (const float*)d_in[18];
    const float* gru_w_ih    = (const float*)d_in[19];
    const float* gru_w_hh    = (const float*)d_in[20];
    const float* gru_b_ih    = (const float*)d_in[21];
    const float* gru_b_hh    = (const float*)d_in[22];
    const float* fc2_w       = (const float*)d_in[23];
    const float* fc2_b       = (const float*)d_in[24];
    const float* merge_out_w = (const float*)d_in[25];
    float* out = (float*)d_out;
    float* ws  = (float*)d_ws;

    hipLaunchKernelGGL(prep_kernel, dim3(414), dim3(256), 0, stream,
                       fc1_own_w, he_w2, he_b2, ha_w2, ha_b2, merge_in_w,
                       gru_w_ih, gru_w_hh, gru_b_ih, gru_b_hh, merge_out_w, ws);
    hipLaunchKernelGGL(main_kernel, dim3(NTOT_/AGB_), dim3(512), 0, stream,
                       own_feats, enemy_feats, ally_feats, hidden, agent_idx, last_act,
                       fc1_own_b, agent_emb, action_emb, he_w1, he_b1, ha_w1, ha_b1,
                       fc2_w, fc2_b, ws, out);
}